// Round 4
// baseline (279.639 us; speedup 1.0000x reference)
//
#include <hip/hip_runtime.h>
#include <stdint.h>

#define CCH 64
#define KK 27
#define SHIFT0 31
#define SHIFT1 31
#define PRELU_SHIFT 25

typedef int v4i __attribute__((ext_vector_type(4)));

__device__ __forceinline__ long long clip127(long long v) {
    return v > 127 ? 127 : (v < -127 ? -127 : v);
}

// repack int8-valued int32 array -> packed int8 (weights arrive as int32 on device)
__global__ void k_pack8(const int* __restrict__ src, int8_t* __restrict__ dst, int n) {
    int i = blockIdx.x * blockDim.x + threadIdx.x;
    if (i < n) dst[i] = (int8_t)src[i];
}

// q0 = clip((x32 * mul0) >> 31) as packed int8 (4 per dword)
__global__ void k_requant0(const int* __restrict__ x,
                           const int* __restrict__ mulp,
                           int* __restrict__ q0,
                           int total4) {
    const long long mul = (long long)(*mulp);
    int i = blockIdx.x * blockDim.x + threadIdx.x;
    const int stride = gridDim.x * blockDim.x;
    for (; i < total4; i += stride) {
        int4 v = ((const int4*)x)[i];
        long long t;
        int r = 0;
        t = ((long long)v.x * mul) >> SHIFT0; t = clip127(t); r |= (int)(t & 0xff);
        t = ((long long)v.y * mul) >> SHIFT0; t = clip127(t); r |= (int)(t & 0xff) << 8;
        t = ((long long)v.z * mul) >> SHIFT0; t = clip127(t); r |= (int)(t & 0xff) << 16;
        t = ((long long)v.w * mul) >> SHIFT0; t = clip127(t); r |= (int)(t & 0xff) << 24;
        q0[i] = r;
    }
}

// MFMA conv: 256 threads = 4 waves; one 16-voxel tile per grid-stride iteration.
// Wave w computes output channels [w*16, w*16+16) for all 16 voxels via
// 27 x mfma_i32_16x16x64_i8 (one per kernel offset, K=64 input channels).
// A (16x64, LDS, padded stride 436 dwords): lane l -> row=l&15, k=(l>>4)*16+j
// B (64x16, registers):                     lane l -> k=(l>>4)*16+j, col=l&15
// D (16x16):                                lane l -> row=(l>>4)*4+r, col=l&15
template <int LAYER>
__global__ void __launch_bounds__(256, 4)
k_conv_mfma(const int8_t* __restrict__ fin,   // [nvox*64] int8 activations
            const int* __restrict__ in_idx,   // [nvox*27]
            const int* __restrict__ mask,     // [nvox*27] (0/1)
            const int8_t* __restrict__ w8,    // [27*64*64] packed int8 (k, out, in)
            const int* __restrict__ bias,     // [64]
            const int* __restrict__ comp,     // [27*64]
            const int* __restrict__ mul1,     // [64]   (layer 1)
            const int* __restrict__ slopep,   // scalar (layer 1)
            const int* __restrict__ x32,      // [nvox*64] residual (layer 2)
            int8_t* __restrict__ q1out,       // layer-1 output
            int* __restrict__ out,            // layer-2 output
            int nvox, int ntiles) {
    __shared__ int s_act[16 * 436];   // 16 voxel rows x 1744B (27*64 data + 16B pad)
    __shared__ int s_mbits[16];

    const int tid  = threadIdx.x;
    const int lane = tid & 63;
    const int wv   = tid >> 6;            // output-channel tile 0..3
    const int col  = wv * 16 + (lane & 15);
    const int srow = lane >> 4;           // K sub-block 0..3
    const int arow = lane & 15;           // A-fragment voxel row

    // --- per-block preloads (reused across grid-stride tiles) ---
    v4i wreg[KK];
#pragma unroll
    for (int k = 0; k < KK; ++k)
        wreg[k] = *(const v4i*)(w8 + ((size_t)(k * CCH + col)) * CCH + srow * 16);

    int comp_r[KK];
#pragma unroll
    for (int k = 0; k < KK; ++k) comp_r[k] = comp[k * CCH + col];

    const int bias_r = bias[col];
    const int mul_r = (LAYER == 1) ? mul1[col] : 0;
    const long long slope = (LAYER == 1) ? (long long)(*slopep) : 0;

    for (int tile = blockIdx.x; tile < ntiles; tile += gridDim.x) {
        const int nb = tile * 16;

        // mask bits per voxel (for epilogue comp term)
        if (tid < 16) {
            const int n = nb + tid;
            int mb = 0;
            if (n < nvox) {
#pragma unroll
                for (int k = 0; k < KK; ++k)
                    mb |= (mask[(size_t)n * KK + k] != 0) << k;
            }
            s_mbits[tid] = mb;
        }

        // gather masked activation rows into LDS: (v,k,seg) -> 16B each
        for (int t = tid; t < 16 * KK * 4; t += 256) {
            const int v   = t / (KK * 4);
            const int rem = t - v * (KK * 4);
            const int k   = rem >> 2;
            const int seg = rem & 3;
            const int n   = nb + v;
            v4i val = {0, 0, 0, 0};
            if (n < nvox && mask[(size_t)n * KK + k]) {
                const int ix = in_idx[(size_t)n * KK + k];
                val = *(const v4i*)(fin + (size_t)ix * CCH + seg * 16);
            }
            *(v4i*)(&s_act[v * 436 + k * 16 + seg * 4]) = val;
        }
        __syncthreads();

        // K-loop: 27 MFMAs accumulating into one 16x16 tile
        v4i acc = {0, 0, 0, 0};
#pragma unroll
        for (int k = 0; k < KK; ++k) {
            v4i a = *(const v4i*)(&s_act[arow * 436 + k * 16 + srow * 4]);
            acc = __builtin_amdgcn_mfma_i32_16x16x64_i8(a, wreg[k], acc, 0, 0, 0);
        }

        // epilogue: + bias + mask.comp, then PReLU/requant (L1) or residual (L2)
        const int vbase = srow * 4;
#pragma unroll
        for (int r = 0; r < 4; ++r) {
            const int n = nb + vbase + r;
            if (n < nvox) {
                int val = acc[r] + bias_r;
                const int mb = s_mbits[vbase + r];
#pragma unroll
                for (int k = 0; k < KK; ++k)
                    val += ((mb >> k) & 1) ? comp_r[k] : 0;
                if (LAYER == 1) {
                    long long p = val;
                    if (val < 0) p = (p * slope) >> PRELU_SHIFT;
                    long long q = (p * (long long)mul_r) >> SHIFT1;
                    q = clip127(q);
                    q1out[(size_t)n * CCH + col] = (int8_t)q;
                } else {
                    out[(size_t)n * CCH + col] = val + x32[(size_t)n * CCH + col];
                }
            }
        }
        __syncthreads();   // protect s_act/s_mbits before next tile's staging
    }
}

extern "C" void kernel_launch(void* const* d_in, const int* in_sizes, int n_in,
                              void* d_out, int out_size, void* d_ws, size_t ws_size,
                              hipStream_t stream) {
    // ALL integer inputs arrive as int32 on device, regardless of reference dtype.
    const int* x32    = (const int*)d_in[0];
    const int* in_idx = (const int*)d_in[1];
    const int* mask   = (const int*)d_in[2];
    const int* w1_32  = (const int*)d_in[3];
    const int* b1     = (const int*)d_in[4];
    const int* comp1  = (const int*)d_in[5];
    const int* w2_32  = (const int*)d_in[6];
    const int* b2     = (const int*)d_in[7];
    const int* comp2  = (const int*)d_in[8];
    const int* mul0   = (const int*)d_in[9];
    const int* mul1   = (const int*)d_in[10];
    const int* slope  = (const int*)d_in[11];

    const int nvox = in_sizes[0] / CCH;                 // 100000
    const int wn = KK * CCH * CCH;                      // 110592 weight elements
    const size_t fbytes = (size_t)nvox * CCH;           // 6.4 MB per int8 feature map
    const size_t falign = (fbytes + 255) & ~(size_t)255;
    const size_t walign = ((size_t)wn + 255) & ~(size_t)255;

    int8_t* q0;
    int8_t* q1;
    int8_t* w1p;
    int8_t* w2p;
    if (ws_size >= 2 * falign + 2 * walign) {
        q0  = (int8_t*)d_ws;
        q1  = q0 + falign;
        w1p = q1 + falign;
        w2p = w1p + walign;
    } else {
        // stage q0 in d_out's bytes (dead after conv1; conv2 rewrites d_out fully)
        q0  = (int8_t*)d_out;
        q1  = (int8_t*)d_ws;
        w1p = q1 + falign;
        w2p = w1p + walign;
    }

    const int pblocks = (wn + 255) / 256;
    k_pack8<<<pblocks, 256, 0, stream>>>(w1_32, w1p, wn);
    k_pack8<<<pblocks, 256, 0, stream>>>(w2_32, w2p, wn);

    {
        const int total4 = (nvox * CCH) / 4;
        int blocks = (total4 + 255) / 256;
        if (blocks > 4096) blocks = 4096;
        k_requant0<<<blocks, 256, 0, stream>>>(x32, mul0, (int*)q0, total4);
    }

    const int ntiles = (nvox + 15) / 16;                // 6250
    int cblocks = 1280;                                 // 4 resident blocks/CU x 256 CUs + slack
    if (cblocks > ntiles) cblocks = ntiles;
    k_conv_mfma<1><<<cblocks, 256, 0, stream>>>(q0, in_idx, mask, w1p, b1, comp1,
                                                mul1, slope, nullptr, q1, nullptr,
                                                nvox, ntiles);
    k_conv_mfma<2><<<cblocks, 256, 0, stream>>>(q1, in_idx, mask, w2p, b2, comp2,
                                                nullptr, nullptr, x32, nullptr,
                                                (int*)d_out, nvox, ntiles);
}

// Round 5
// 131.597 us; speedup vs baseline: 2.1250x; 2.1250x over previous
//
#include <hip/hip_runtime.h>
#include <stdint.h>

#define CCH 64
#define KK 27
#define SHIFT0 31
#define SHIFT1 31
#define PRELU_SHIFT 25

typedef int v4i __attribute__((ext_vector_type(4)));

__device__ __forceinline__ long long clip127(long long v) {
    return v > 127 ? 127 : (v < -127 ? -127 : v);
}

// async global->LDS, 16 B per lane; LDS dest is the WAVE-UNIFORM base,
// hardware scatters lane l to base + l*16. Global src is per-lane.
__device__ __forceinline__ void gload_lds16(const void* g, void* lds_base) {
    __builtin_amdgcn_global_load_lds(
        (const __attribute__((address_space(1))) unsigned int*)g,
        (__attribute__((address_space(3))) unsigned int*)lds_base,
        16, 0, 0);
}

// repack int8-valued int32 array -> packed int8 (weights arrive as int32 on device)
__global__ void k_pack8(const int* __restrict__ src, int8_t* __restrict__ dst, int n) {
    int i = blockIdx.x * blockDim.x + threadIdx.x;
    if (i < n) dst[i] = (int8_t)src[i];
}

// q0 = clip((x32 * mul0) >> 31) packed int8; also zero-fills the 256 B zero page
__global__ void k_requant0(const int* __restrict__ x,
                           const int* __restrict__ mulp,
                           int* __restrict__ q0,
                           int* __restrict__ zpage,
                           int total4) {
    if (blockIdx.x == 0 && threadIdx.x < 64) zpage[threadIdx.x] = 0;
    const long long mul = (long long)(*mulp);
    int i = blockIdx.x * blockDim.x + threadIdx.x;
    const int stride = gridDim.x * blockDim.x;
    for (; i < total4; i += stride) {
        int4 v = ((const int4*)x)[i];
        long long t;
        int r = 0;
        t = ((long long)v.x * mul) >> SHIFT0; t = clip127(t); r |= (int)(t & 0xff);
        t = ((long long)v.y * mul) >> SHIFT0; t = clip127(t); r |= (int)(t & 0xff) << 8;
        t = ((long long)v.z * mul) >> SHIFT0; t = clip127(t); r |= (int)(t & 0xff) << 16;
        t = ((long long)v.w * mul) >> SHIFT0; t = clip127(t); r |= (int)(t & 0xff) << 24;
        q0[i] = r;
    }
}

// MFMA conv: 256 threads = 4 waves; one 16-voxel tile per grid-stride iteration.
// Wave wv computes output channels [wv*16, wv*16+16) for all 16 voxels via
// 27 x mfma_i32_16x16x64_i8. A-tile staged by global_load_lds (1 KB per k-slice).
// A (16x64, LDS [k][row*64+seg*16]): lane l -> row=l&15, k=(l>>4)*16+j
// B (64x16, registers):              lane l -> k=(l>>4)*16+j, col=l&15
// D (16x16):                         lane l -> row=(l>>4)*4+r, col=l&15
template <int LAYER>
__global__ void __launch_bounds__(256)
k_conv_mfma(const int8_t* __restrict__ fin,   // [nvox*64] int8 activations
            const int* __restrict__ in_idx,   // [nvox*27]
            const int* __restrict__ mask,     // [nvox*27] (0/1)
            const int8_t* __restrict__ w8,    // [27*64*64] packed int8 (k, out, in)
            const int* __restrict__ bias,     // [64]
            const int* __restrict__ comp,     // [27*64]
            const int* __restrict__ mul1,     // [64]   (layer 1)
            const int* __restrict__ slopep,   // scalar (layer 1)
            const int* __restrict__ x32,      // [nvox*64] residual (layer 2)
            const int8_t* __restrict__ zpage, // 64+ B of zeros
            int8_t* __restrict__ q1out,       // layer-1 output
            int* __restrict__ out,            // layer-2 output
            int nvox, int ntiles) {
    __shared__ int8_t s_act[KK * 1024];   // [k][row*64 + seg*16]
    __shared__ int s_idxm[16 * KK];       // masked idx (or -1)
    __shared__ int s_mbits[16];

    const int tid  = threadIdx.x;
    const int lane = tid & 63;
    const int wv   = tid >> 6;            // output-channel tile 0..3
    const int col  = wv * 16 + (lane & 15);
    const int srow = lane >> 4;           // K sub-block 0..3
    const int arow = lane & 15;           // A-fragment voxel row
    const int grow = lane >> 2;           // staging voxel row 0..15
    const int gseg = lane & 3;            // staging 16-B segment

    // --- per-block preloads (reused across grid-stride tiles) ---
    v4i wreg[KK];
#pragma unroll
    for (int k = 0; k < KK; ++k)
        wreg[k] = *(const v4i*)(w8 + ((size_t)(k * CCH + col)) * CCH + srow * 16);

    int comp_r[KK];
#pragma unroll
    for (int k = 0; k < KK; ++k) comp_r[k] = comp[k * CCH + col];

    const int bias_r = bias[col];
    const int mul_r = (LAYER == 1) ? mul1[col] : 0;
    const long long slope = (LAYER == 1) ? (long long)(*slopep) : 0;

    for (int tile = blockIdx.x; tile < ntiles; tile += gridDim.x) {
        const int nb = tile * 16;

        // coalesced: s_idxm[t] = mask ? idx : -1   (t spans 16 voxels x 27 k)
        for (int t = tid; t < 16 * KK; t += 256) {
            const int n = nb + t / KK;
            int v = -1;
            if (n < nvox && mask[(size_t)nb * KK + t] != 0)
                v = in_idx[(size_t)nb * KK + t];
            s_idxm[t] = v;
        }
        __syncthreads();

        // async-stage A-tile: wave wv issues k = wv, wv+4, ... (7 max, back-to-back)
        for (int k = wv; k < KK; k += 4) {
            const int v = s_idxm[grow * KK + k];
            const int8_t* src = (v >= 0) ? (fin + (size_t)v * CCH + gseg * 16)
                                         : (zpage + gseg * 16);
            gload_lds16(src, s_act + k * 1024);
        }

        // pack per-voxel mask bits for the epilogue comp term
        if (tid < 16) {
            int mb = 0;
#pragma unroll
            for (int k = 0; k < KK; ++k)
                mb |= (s_idxm[tid * KK + k] >= 0) << k;
            s_mbits[tid] = mb;
        }
        __syncthreads();   // drains vmcnt for the global_load_lds + publishes s_mbits

        // K-loop: 27 MFMAs accumulating into one 16x16 tile
        v4i acc = {0, 0, 0, 0};
#pragma unroll
        for (int k = 0; k < KK; ++k) {
            v4i a = *(const v4i*)(s_act + k * 1024 + arow * 64 + srow * 16);
            acc = __builtin_amdgcn_mfma_i32_16x16x64_i8(a, wreg[k], acc, 0, 0, 0);
        }

        // epilogue: + bias + mask.comp, then PReLU/requant (L1) or residual (L2)
        const int vbase = srow * 4;
#pragma unroll
        for (int r = 0; r < 4; ++r) {
            const int n = nb + vbase + r;
            if (n < nvox) {
                int val = acc[r] + bias_r;
                const int mb = s_mbits[vbase + r];
#pragma unroll
                for (int k = 0; k < KK; ++k)
                    val += ((mb >> k) & 1) ? comp_r[k] : 0;
                if (LAYER == 1) {
                    long long p = val;
                    if (val < 0) p = (p * slope) >> PRELU_SHIFT;
                    long long q = (p * (long long)mul_r) >> SHIFT1;
                    q = clip127(q);
                    q1out[(size_t)n * CCH + col] = (int8_t)q;
                } else {
                    out[(size_t)n * CCH + col] = val + x32[(size_t)n * CCH + col];
                }
            }
        }
        __syncthreads();   // protect s_act/s_idxm/s_mbits before next tile's staging
    }
}

extern "C" void kernel_launch(void* const* d_in, const int* in_sizes, int n_in,
                              void* d_out, int out_size, void* d_ws, size_t ws_size,
                              hipStream_t stream) {
    // ALL integer inputs arrive as int32 on device, regardless of reference dtype.
    const int* x32    = (const int*)d_in[0];
    const int* in_idx = (const int*)d_in[1];
    const int* mask   = (const int*)d_in[2];
    const int* w1_32  = (const int*)d_in[3];
    const int* b1     = (const int*)d_in[4];
    const int* comp1  = (const int*)d_in[5];
    const int* w2_32  = (const int*)d_in[6];
    const int* b2     = (const int*)d_in[7];
    const int* comp2  = (const int*)d_in[8];
    const int* mul0   = (const int*)d_in[9];
    const int* mul1   = (const int*)d_in[10];
    const int* slope  = (const int*)d_in[11];

    const int nvox = in_sizes[0] / CCH;                 // 100000
    const int wn = KK * CCH * CCH;                      // 110592 weight elements
    const size_t fbytes = (size_t)nvox * CCH;           // 6.4 MB per int8 feature map
    const size_t falign = (fbytes + 255) & ~(size_t)255;
    const size_t walign = ((size_t)wn + 255) & ~(size_t)255;

    int8_t* q0;
    int8_t* q1;
    int8_t* w1p;
    int8_t* w2p;
    if (ws_size >= 2 * falign + 2 * walign + 256) {
        q0  = (int8_t*)d_ws;
        q1  = q0 + falign;
        w1p = q1 + falign;
        w2p = w1p + walign;
    } else {
        // stage q0 in d_out's bytes (dead after conv1; conv2 rewrites d_out fully)
        q0  = (int8_t*)d_out;
        q1  = (int8_t*)d_ws;
        w1p = q1 + falign;
        w2p = w1p + walign;
    }
    int8_t* zpage = w2p + walign;   // 256 B zero page

    const int pblocks = (wn + 255) / 256;
    k_pack8<<<pblocks, 256, 0, stream>>>(w1_32, w1p, wn);
    k_pack8<<<pblocks, 256, 0, stream>>>(w2_32, w2p, wn);

    {
        const int total4 = (nvox * CCH) / 4;
        int blocks = (total4 + 255) / 256;
        if (blocks > 4096) blocks = 4096;
        k_requant0<<<blocks, 256, 0, stream>>>(x32, mul0, (int*)q0, (int*)zpage, total4);
    }

    const int ntiles = (nvox + 15) / 16;                // 6250
    int cblocks = 1024;                                 // ~6 tiles/block, fills residency
    if (cblocks > ntiles) cblocks = ntiles;
    k_conv_mfma<1><<<cblocks, 256, 0, stream>>>(q0, in_idx, mask, w1p, b1, comp1,
                                                mul1, slope, nullptr, zpage,
                                                q1, nullptr, nvox, ntiles);
    k_conv_mfma<2><<<cblocks, 256, 0, stream>>>(q1, in_idx, mask, w2p, b2, comp2,
                                                nullptr, nullptr, x32, zpage,
                                                nullptr, (int*)d_out, nvox, ntiles);
}

// Round 6
// 124.158 us; speedup vs baseline: 2.2523x; 1.0599x over previous
//
#include <hip/hip_runtime.h>
#include <stdint.h>

#define CCH 64
#define KK 27
#define KK2 28          // 27 conv slices + 1 affine (comp/bias) slice
#define SHIFT0 31
#define SHIFT1 31
#define PRELU_SHIFT 25

typedef int v4i __attribute__((ext_vector_type(4)));

__device__ __forceinline__ long long clip127(long long v) {
    return v > 127 ? 127 : (v < -127 ? -127 : v);
}

// async global->LDS, 16 B per lane; LDS dest is the WAVE-UNIFORM base,
// hardware places lane l at base + l*16. Global src is per-lane.
__device__ __forceinline__ void gload_lds16(const void* g, void* lds_base) {
    __builtin_amdgcn_global_load_lds(
        (const __attribute__((address_space(1))) unsigned int*)g,
        (__attribute__((address_space(3))) unsigned int*)lds_base,
        16, 0, 0);
}

// repack int8-valued int32 array -> packed int8 (weights arrive as int32 on device)
__global__ void k_pack8(const int* __restrict__ src, int8_t* __restrict__ dst, int n) {
    int i = blockIdx.x * blockDim.x + threadIdx.x;
    if (i < n) dst[i] = (int8_t)src[i];
}

// build slice 27 of w_ext: B[j][col] encodes comp (split 4*hi+lo) and bias (64*hi+lo)
__global__ void k_packc(const int* __restrict__ comp, const int* __restrict__ bias,
                        int8_t* __restrict__ dst /* w_ext + 27*4096 */) {
    int t = blockIdx.x * blockDim.x + threadIdx.x;   // 0..4095
    if (t >= CCH * CCH) return;
    const int col = t >> 6;
    const int j   = t & 63;
    int v;
    if (j < 27)       v = comp[j * CCH + col] >> 2;          // pairs with A=4*mask
    else if (j < 54)  v = comp[(j - 27) * CCH + col] & 3;    // pairs with A=1*mask
    else if (j == 54) v = bias[col] >> 6;                    // pairs with A=64
    else if (j == 55) v = bias[col] & 63;                    // pairs with A=1
    else              v = 0;
    dst[col * 64 + j] = (int8_t)v;
}

// q0 = clip((x32 * mul0) >> 31) packed int8; also zero-fills the 256 B zero page
__global__ void k_requant0(const int* __restrict__ x,
                           const int* __restrict__ mulp,
                           int* __restrict__ q0,
                           int* __restrict__ zpage,
                           int total4) {
    if (blockIdx.x == 0 && threadIdx.x < 64) zpage[threadIdx.x] = 0;
    const long long mul = (long long)(*mulp);
    int i = blockIdx.x * blockDim.x + threadIdx.x;
    const int stride = gridDim.x * blockDim.x;
    for (; i < total4; i += stride) {
        int4 v = ((const int4*)x)[i];
        long long t;
        int r = 0;
        t = ((long long)v.x * mul) >> SHIFT0; t = clip127(t); r |= (int)(t & 0xff);
        t = ((long long)v.y * mul) >> SHIFT0; t = clip127(t); r |= (int)(t & 0xff) << 8;
        t = ((long long)v.z * mul) >> SHIFT0; t = clip127(t); r |= (int)(t & 0xff) << 16;
        t = ((long long)v.w * mul) >> SHIFT0; t = clip127(t); r |= (int)(t & 0xff) << 24;
        q0[i] = r;
    }
}

// MFMA conv: 256 threads = 4 waves; one 16-voxel tile per grid-stride iteration.
// Wave wv computes output channels [wv*16,+16) for 16 voxels via 28 x
// mfma_i32_16x16x64_i8 (27 conv slices + 1 affine slice = comp+bias folded).
// A-tile LDS swizzle (bank-conflict-free reads): slot s of row r holds global
// segment s ^ SW(r), SW(r) = (r ^ (r>>2)) & 3 — applied on the gather SOURCE
// address (gload_lds dest must stay linear) and on the ds_read address.
template <int LAYER>
__global__ void __launch_bounds__(256)
k_conv_mfma(const int8_t* __restrict__ fin,   // [nvox*64] int8 activations
            const int* __restrict__ in_idx,   // [nvox*27]
            const int* __restrict__ mask,     // [nvox*27] (0/1)
            const int8_t* __restrict__ wext,  // [28*64*64] packed int8
            const int* __restrict__ mul1,     // [64]   (layer 1)
            const int* __restrict__ slopep,   // scalar (layer 1)
            const int* __restrict__ x32,      // [nvox*64] residual (layer 2)
            const int8_t* __restrict__ zpage, // 64+ B of zeros
            int8_t* __restrict__ q1out,       // layer-1 output
            int* __restrict__ out,            // layer-2 output
            int nvox, int ntiles) {
    __shared__ int8_t s_act[KK2 * 1024];  // [k][row*64 + slot*16], swizzled slots
    __shared__ int s_idxm[16 * KK];       // masked idx (or -1)

    const int tid  = threadIdx.x;
    const int lane = tid & 63;
    const int wv   = tid >> 6;            // output-channel tile 0..3
    const int col  = wv * 16 + (lane & 15);
    const int srow = lane >> 4;           // K sub-block 0..3
    const int arow = lane & 15;           // A-fragment voxel row
    const int grow = lane >> 2;           // staging voxel row 0..15
    const int gseg = lane & 3;            // staging slot 0..3

    // --- per-block preloads (reused across grid-stride tiles) ---
    v4i wreg[KK2];
#pragma unroll
    for (int k = 0; k < KK2; ++k)
        wreg[k] = *(const v4i*)(wext + ((size_t)(k * CCH + col)) * CCH + srow * 16);

    const int mul_r = (LAYER == 1) ? mul1[col] : 0;
    const long long slope = (LAYER == 1) ? (long long)(*slopep) : 0;

    // fixed per-lane offsets
    const int sw_g = (grow ^ (grow >> 2)) & 3;
    const int gsrc_off = (gseg ^ sw_g) * 16;             // swizzled source segment
    const int sw_a = (arow ^ (arow >> 2)) & 3;
    const int aread_off = arow * 64 + ((srow ^ sw_a) * 16);
    // affine-slice writer: thread -> (row wrow, dword wj4)
    const int wrow = tid >> 4;
    const int wj4  = tid & 15;
    const int sw_w = (wrow ^ (wrow >> 2)) & 3;
    const int waddr = 27 * 1024 + wrow * 64 + (((wj4 >> 2) ^ sw_w) * 16) + (wj4 & 3) * 4;

    for (int tile = blockIdx.x; tile < ntiles; tile += gridDim.x) {
        const int nb = tile * 16;

        // coalesced: s_idxm[t] = mask ? idx : -1
        for (int t = tid; t < 16 * KK; t += 256) {
            const int n = nb + t / KK;
            int v = -1;
            if (n < nvox && mask[(size_t)nb * KK + t] != 0)
                v = in_idx[(size_t)nb * KK + t];
            s_idxm[t] = v;
        }
        __syncthreads();

        // async-stage conv slices: wave wv issues k = wv, wv+4, ... (7 each)
        for (int k = wv; k < KK; k += 4) {
            const int v = s_idxm[grow * KK + k];
            const int8_t* src = (v >= 0) ? (fin + (size_t)v * CCH + gsrc_off)
                                         : (zpage + gsrc_off);
            gload_lds16(src, s_act + k * 1024);
        }

        // build affine A-slice (k=27): bytes [4*mask | 1*mask | 64 | 1 | 0]
        {
            int pk = 0;
#pragma unroll
            for (int b = 0; b < 4; ++b) {
                const int j = wj4 * 4 + b;
                int bv;
                if (j < 27)       bv = (s_idxm[wrow * KK + j] >= 0) ? 4 : 0;
                else if (j < 54)  bv = (s_idxm[wrow * KK + (j - 27)] >= 0) ? 1 : 0;
                else if (j == 54) bv = 64;
                else if (j == 55) bv = 1;
                else              bv = 0;
                pk |= bv << (8 * b);
            }
            *(int*)(s_act + waddr) = pk;
        }
        __syncthreads();   // drains gload_lds (vmcnt) + ds_writes (lgkm)

        // K-loop: 28 MFMAs (conv + affine) into one 16x16 tile
        v4i acc = {0, 0, 0, 0};
#pragma unroll
        for (int k = 0; k < KK2; ++k) {
            v4i a = *(const v4i*)(s_act + k * 1024 + aread_off);
            acc = __builtin_amdgcn_mfma_i32_16x16x64_i8(a, wreg[k], acc, 0, 0, 0);
        }

        // epilogue: PReLU/requant (L1) or residual add (L2) — affine already in acc
        const int vbase = srow * 4;
#pragma unroll
        for (int r = 0; r < 4; ++r) {
            const int n = nb + vbase + r;
            if (n < nvox) {
                const int val = acc[r];
                if (LAYER == 1) {
                    long long p = val;
                    if (val < 0) p = (p * slope) >> PRELU_SHIFT;
                    long long q = (p * (long long)mul_r) >> SHIFT1;
                    q = clip127(q);
                    q1out[(size_t)n * CCH + col] = (int8_t)q;
                } else {
                    out[(size_t)n * CCH + col] = val + x32[(size_t)n * CCH + col];
                }
            }
        }
        __syncthreads();   // protect s_act/s_idxm before next tile's staging
    }
}

extern "C" void kernel_launch(void* const* d_in, const int* in_sizes, int n_in,
                              void* d_out, int out_size, void* d_ws, size_t ws_size,
                              hipStream_t stream) {
    // ALL integer inputs arrive as int32 on device, regardless of reference dtype.
    const int* x32    = (const int*)d_in[0];
    const int* in_idx = (const int*)d_in[1];
    const int* mask   = (const int*)d_in[2];
    const int* w1_32  = (const int*)d_in[3];
    const int* b1     = (const int*)d_in[4];
    const int* comp1  = (const int*)d_in[5];
    const int* w2_32  = (const int*)d_in[6];
    const int* b2     = (const int*)d_in[7];
    const int* comp2  = (const int*)d_in[8];
    const int* mul0   = (const int*)d_in[9];
    const int* mul1   = (const int*)d_in[10];
    const int* slope  = (const int*)d_in[11];

    const int nvox = in_sizes[0] / CCH;                 // 100000
    const int wn = KK * CCH * CCH;                      // 110592 conv weights
    const size_t wext_b = (size_t)KK2 * CCH * CCH;      // 114688 per layer
    const size_t fbytes = (size_t)nvox * CCH;           // 6.4 MB per int8 feature map
    const size_t falign = (fbytes + 255) & ~(size_t)255;
    const size_t walign = (wext_b + 255) & ~(size_t)255;

    int8_t* q0;
    int8_t* q1;
    int8_t* w1e;
    int8_t* w2e;
    if (ws_size >= 2 * falign + 2 * walign + 256) {
        q0  = (int8_t*)d_ws;
        q1  = q0 + falign;
        w1e = q1 + falign;
        w2e = w1e + walign;
    } else {
        // stage q0 in d_out's bytes (dead after conv1; conv2 rewrites d_out fully)
        q0  = (int8_t*)d_out;
        q1  = (int8_t*)d_ws;
        w1e = q1 + falign;
        w2e = w1e + walign;
    }
    int8_t* zpage = w2e + walign;   // 256 B zero page

    const int pblocks = (wn + 255) / 256;
    k_pack8<<<pblocks, 256, 0, stream>>>(w1_32, w1e, wn);
    k_pack8<<<pblocks, 256, 0, stream>>>(w2_32, w2e, wn);
    k_packc<<<16, 256, 0, stream>>>(comp1, b1, w1e + (size_t)KK * CCH * CCH);
    k_packc<<<16, 256, 0, stream>>>(comp2, b2, w2e + (size_t)KK * CCH * CCH);

    {
        const int total4 = (nvox * CCH) / 4;
        int blocks = (total4 + 255) / 256;
        if (blocks > 4096) blocks = 4096;
        k_requant0<<<blocks, 256, 0, stream>>>(x32, mul0, (int*)q0, (int*)zpage, total4);
    }

    const int ntiles = (nvox + 15) / 16;                // 6250
    int cblocks = 1024;
    if (cblocks > ntiles) cblocks = ntiles;
    k_conv_mfma<1><<<cblocks, 256, 0, stream>>>(q0, in_idx, mask, w1e,
                                                mul1, slope, nullptr, zpage,
                                                q1, nullptr, nvox, ntiles);
    k_conv_mfma<2><<<cblocks, 256, 0, stream>>>(q1, in_idx, mask, w2e,
                                                nullptr, nullptr, x32, zpage,
                                                nullptr, (int*)d_out, nvox, ntiles);
}

// Round 7
// 81.108 us; speedup vs baseline: 3.4477x; 1.5308x over previous
//
#include <hip/hip_runtime.h>
#include <stdint.h>

#define CCH 64
#define KK 27
#define KK2 28          // 27 conv slices + 1 affine (comp/bias) slice
#define SHIFT0 31
#define SHIFT1 31
#define PRELU_SHIFT 25

typedef int v4i __attribute__((ext_vector_type(4)));

__device__ __forceinline__ long long clip127(long long v) {
    return v > 127 ? 127 : (v < -127 ? -127 : v);
}

// async global->LDS, 16 B per lane; LDS dest is the WAVE-UNIFORM base,
// hardware places lane l at base + l*16. Global src is per-lane.
__device__ __forceinline__ void gload_lds16(const void* g, void* lds_base) {
    __builtin_amdgcn_global_load_lds(
        (const __attribute__((address_space(1))) unsigned int*)g,
        (__attribute__((address_space(3))) unsigned int*)lds_base,
        16, 0, 0);
}

// repack int8-valued int32 array -> packed int8 (weights arrive as int32 on device)
__global__ void k_pack8(const int* __restrict__ src, int8_t* __restrict__ dst, int n) {
    int i = blockIdx.x * blockDim.x + threadIdx.x;
    if (i < n) dst[i] = (int8_t)src[i];
}

// build slice 27 of w_ext: B[j][col] encodes comp (split 4*hi+lo) and bias (64*hi+lo)
__global__ void k_packc(const int* __restrict__ comp, const int* __restrict__ bias,
                        int8_t* __restrict__ dst /* w_ext + 27*4096 */) {
    int t = blockIdx.x * blockDim.x + threadIdx.x;   // 0..4095
    if (t >= CCH * CCH) return;
    const int col = t >> 6;
    const int j   = t & 63;
    int v;
    if (j < 27)       v = comp[j * CCH + col] >> 2;          // pairs with A=4*mask
    else if (j < 54)  v = comp[(j - 27) * CCH + col] & 3;    // pairs with A=1*mask
    else if (j == 54) v = bias[col] >> 6;                    // pairs with A=64
    else if (j == 55) v = bias[col] & 63;                    // pairs with A=1
    else              v = 0;
    dst[col * 64 + j] = (int8_t)v;
}

// q0 = clip((x32 * mul0) >> 31) packed int8; also zero-fills the 256 B zero page
__global__ void k_requant0(const int* __restrict__ x,
                           const int* __restrict__ mulp,
                           int* __restrict__ q0,
                           int* __restrict__ zpage,
                           int total4) {
    if (blockIdx.x == 0 && threadIdx.x < 64) zpage[threadIdx.x] = 0;
    const long long mul = (long long)(*mulp);
    int i = blockIdx.x * blockDim.x + threadIdx.x;
    const int stride = gridDim.x * blockDim.x;
    for (; i < total4; i += stride) {
        int4 v = ((const int4*)x)[i];
        long long t;
        int r = 0;
        t = ((long long)v.x * mul) >> SHIFT0; t = clip127(t); r |= (int)(t & 0xff);
        t = ((long long)v.y * mul) >> SHIFT0; t = clip127(t); r |= (int)(t & 0xff) << 8;
        t = ((long long)v.z * mul) >> SHIFT0; t = clip127(t); r |= (int)(t & 0xff) << 16;
        t = ((long long)v.w * mul) >> SHIFT0; t = clip127(t); r |= (int)(t & 0xff) << 24;
        q0[i] = r;
    }
}

// Pipelined MFMA conv: 256 threads = 4 waves; 16-voxel tiles, grid-stride.
// 2-deep pipeline: while MFMAs consume s_act[cur] (tile t), gathers for tile
// t+1 stream into s_act[cur^1] via global_load_lds, and idx/mask for tile t+2
// prefetch into registers. ONE raw s_barrier per tile with counted vmcnt(4)
// (the 4 epilogue stores stay in flight; gathers are drained, idx loads are
// waited by the compiler's exact auto-waitcnt at first use).
// REQUIRES nvox % 16 == 0 (true here: 100000 = 6250*16).
template <int LAYER>
__global__ void __launch_bounds__(256)
k_conv_pipe(const int8_t* __restrict__ fin,   // [nvox*64] int8 activations
            const int* __restrict__ in_idx,   // [nvox*27]
            const int* __restrict__ mask,     // [nvox*27] (0/1)
            const int8_t* __restrict__ wext,  // [28*64*64] packed int8
            const int* __restrict__ mul1,     // [64]   (layer 1)
            const int* __restrict__ slopep,   // scalar (layer 1)
            const int* __restrict__ x32,      // [nvox*64] residual (layer 2)
            const int8_t* __restrict__ zpage, // 64+ B of zeros
            int8_t* __restrict__ q1out,       // layer-1 output
            int* __restrict__ out,            // layer-2 output
            int ntiles) {
    __shared__ int8_t s_act[2][KK2 * 1024];   // [buf][k][row*64 + slot*16] swizzled
    __shared__ int    s_idxm[2][16 * KK];     // [slot][voxel*27+k]: idx or -1
    __shared__ int8_t s_dump[1024];           // dummy gather target (wave 3)

    const int tid  = threadIdx.x;
    const int lane = tid & 63;
    const int wv   = tid >> 6;            // output-channel tile 0..3
    const int col  = wv * 16 + (lane & 15);
    const int srow = lane >> 4;           // K sub-block 0..3
    const int arow = lane & 15;           // A-fragment voxel row
    const int grow = lane >> 2;           // staging voxel row 0..15
    const int gseg = lane & 3;            // staging slot 0..3

    // --- per-block preloads ---
    v4i wreg[KK2];
#pragma unroll
    for (int k = 0; k < KK2; ++k)
        wreg[k] = *(const v4i*)(wext + ((size_t)(k * CCH + col)) * CCH + srow * 16);

    const int mul_r = (LAYER == 1) ? mul1[col] : 0;
    const long long slope = (LAYER == 1) ? (long long)(*slopep) : 0;

    // swizzled offsets (source-side swizzle; gload_lds dest stays linear)
    const int sw_g = (grow ^ (grow >> 2)) & 3;
    const int gsrc_off = (gseg ^ sw_g) * 16;
    const int sw_a = (arow ^ (arow >> 2)) & 3;
    const int aread_off = arow * 64 + ((srow ^ sw_a) * 16);
    // affine-slice writer mapping
    const int wrow = tid >> 4;
    const int wj4  = tid & 15;
    const int sw_w = (wrow ^ (wrow >> 2)) & 3;
    const int woff = wrow * 64 + (((wj4 >> 2) ^ sw_w) * 16) + (wj4 & 3) * 4;
    // idx/mask loader entries (uniform 2+2 loads per thread; e1 dups are benign)
    const int e0 = tid;
    const int e1 = (tid + 256 > 431) ? 431 : tid + 256;

    const int stride = gridDim.x;
    const int t0 = blockIdx.x;
    if (t0 >= ntiles) return;
    const int cnt = (ntiles - 1 - t0) / stride + 1;

    // ---- prologue: idxm[t0]->slot0; gathers t0->buf0; idxm[t1]->slot1 ----
    int pa0, pa1, pm0, pm1;
    {
        const size_t base = (size_t)t0 * (16 * KK);
        pa0 = in_idx[base + e0]; pm0 = mask[base + e0];
        pa1 = in_idx[base + e1]; pm1 = mask[base + e1];
        s_idxm[0][e0] = pm0 ? pa0 : -1;
        s_idxm[0][e1] = pm1 ? pa1 : -1;
    }
    {
        const int t1 = (t0 + stride < ntiles) ? t0 + stride : ntiles - 1;
        const size_t base = (size_t)t1 * (16 * KK);
        pa0 = in_idx[base + e0]; pm0 = mask[base + e0];
        pa1 = in_idx[base + e1]; pm1 = mask[base + e1];
    }
    asm volatile("s_waitcnt lgkmcnt(0)" ::: "memory");
    __builtin_amdgcn_s_barrier();
    // gathers + affine for tile t0 into buf 0 (reads s_idxm[0])
#pragma unroll
    for (int j = 0; j < 7; ++j) {
        const int k = wv + 4 * j;
        const bool real = (k < KK);
        const int kk = real ? k : 0;
        const int v = real ? s_idxm[0][grow * KK + kk] : -1;
        const int8_t* src = (v >= 0) ? (fin + (size_t)v * CCH + gsrc_off)
                                     : (zpage + gsrc_off);
        int8_t* dst = real ? (&s_act[0][0] + kk * 1024) : &s_dump[0];
        gload_lds16(src, dst);
    }
    {
        int pk = 0;
#pragma unroll
        for (int b = 0; b < 4; ++b) {
            const int j = wj4 * 4 + b;
            int bv = 0;
            if (j < 27)       bv = (s_idxm[0][wrow * KK + j] >= 0) ? 4 : 0;
            else if (j < 54)  bv = (s_idxm[0][wrow * KK + (j - 27)] >= 0) ? 1 : 0;
            else if (j == 54) bv = 64;
            else if (j == 55) bv = 1;
            pk |= bv << (8 * b);
        }
        *(int*)(&s_act[0][0] + 27 * 1024 + woff) = pk;
    }
    asm volatile("s_waitcnt vmcnt(0)" ::: "memory");   // t0 gathers + t1 idx done
    s_idxm[1][e0] = pm0 ? pa0 : -1;
    s_idxm[1][e1] = pm1 ? pa1 : -1;
    asm volatile("s_waitcnt lgkmcnt(0)" ::: "memory");
    __builtin_amdgcn_s_barrier();
    __builtin_amdgcn_sched_barrier(0);

    // ---- main loop: one barrier per tile ----
    for (int i = 0; i < cnt; ++i) {
        const int cur = i & 1;
        const int t  = t0 + i * stride;
        const int nb = t * 16;
        const int vbase = srow * 4;

        // (a) prefetch idx/mask of tile t+2 -> regs; x32 rows of tile t (L2)
        int tp2 = t + 2 * stride; if (tp2 >= ntiles) tp2 = ntiles - 1;
        const size_t base2 = (size_t)tp2 * (16 * KK);
        const int qa0 = in_idx[base2 + e0]; const int qm0 = mask[base2 + e0];
        const int qa1 = in_idx[base2 + e1]; const int qm1 = mask[base2 + e1];
        int xr0 = 0, xr1 = 0, xr2 = 0, xr3 = 0;
        if (LAYER == 2) {
            xr0 = x32[(size_t)(nb + vbase + 0) * CCH + col];
            xr1 = x32[(size_t)(nb + vbase + 1) * CCH + col];
            xr2 = x32[(size_t)(nb + vbase + 2) * CCH + col];
            xr3 = x32[(size_t)(nb + vbase + 3) * CCH + col];
        }

        // (b) issue gathers + affine for tile t+1 into buf cur^1 (slot (i+1)&1)
        {
            const int slot = (i + 1) & 1;
            int8_t* actn = &s_act[cur ^ 1][0];
#pragma unroll
            for (int j = 0; j < 7; ++j) {
                const int k = wv + 4 * j;
                const bool real = (k < KK);
                const int kk = real ? k : 0;
                const int v = real ? s_idxm[slot][grow * KK + kk] : -1;
                const int8_t* src = (v >= 0) ? (fin + (size_t)v * CCH + gsrc_off)
                                             : (zpage + gsrc_off);
                int8_t* dst = real ? (actn + kk * 1024) : &s_dump[0];
                gload_lds16(src, dst);
            }
            int pk = 0;
#pragma unroll
            for (int b = 0; b < 4; ++b) {
                const int j = wj4 * 4 + b;
                int bv = 0;
                if (j < 27)       bv = (s_idxm[slot][wrow * KK + j] >= 0) ? 4 : 0;
                else if (j < 54)  bv = (s_idxm[slot][wrow * KK + (j - 27)] >= 0) ? 1 : 0;
                else if (j == 54) bv = 64;
                else if (j == 55) bv = 1;
                pk |= bv << (8 * b);
            }
            *(int*)(actn + 27 * 1024 + woff) = pk;
        }

        // (c) 28 MFMAs on buf cur (gathers for t drained at end of prev iter)
        v4i acc = {0, 0, 0, 0};
        const int8_t* actc = &s_act[cur][0];
#pragma unroll
        for (int k = 0; k < KK2; ++k) {
            v4i a = *(const v4i*)(actc + k * 1024 + aread_off);
            acc = __builtin_amdgcn_mfma_i32_16x16x64_i8(a, wreg[k], acc, 0, 0, 0);
        }

        // pin: everything above (incl. gathers) issues before the stores below,
        // so vmcnt(4) == "all gathers done, stores may fly"
        __builtin_amdgcn_sched_barrier(0);

        // (d) epilogue stores for tile t (exactly 4 vmem stores per thread)
        if (LAYER == 1) {
#pragma unroll
            for (int r = 0; r < 4; ++r) {
                long long p = acc[r];
                if (p < 0) p = (p * slope) >> PRELU_SHIFT;
                long long q = (p * (long long)mul_r) >> SHIFT1;
                q = clip127(q);
                q1out[(size_t)(nb + vbase + r) * CCH + col] = (int8_t)q;
            }
        } else {
            out[(size_t)(nb + vbase + 0) * CCH + col] = acc[0] + xr0;
            out[(size_t)(nb + vbase + 1) * CCH + col] = acc[1] + xr1;
            out[(size_t)(nb + vbase + 2) * CCH + col] = acc[2] + xr2;
            out[(size_t)(nb + vbase + 3) * CCH + col] = acc[3] + xr3;
        }

        // (e) publish idxm[t+2] into slot i&1 (dead since prev iter)
        s_idxm[cur][e0] = qm0 ? qa0 : -1;
        s_idxm[cur][e1] = qm1 ? qa1 : -1;

        asm volatile("s_waitcnt vmcnt(4)" ::: "memory");   // gathers done, stores in flight
        asm volatile("s_waitcnt lgkmcnt(0)" ::: "memory");
        __builtin_amdgcn_s_barrier();
        __builtin_amdgcn_sched_barrier(0);
    }
}

extern "C" void kernel_launch(void* const* d_in, const int* in_sizes, int n_in,
                              void* d_out, int out_size, void* d_ws, size_t ws_size,
                              hipStream_t stream) {
    // ALL integer inputs arrive as int32 on device, regardless of reference dtype.
    const int* x32    = (const int*)d_in[0];
    const int* in_idx = (const int*)d_in[1];
    const int* mask   = (const int*)d_in[2];
    const int* w1_32  = (const int*)d_in[3];
    const int* b1     = (const int*)d_in[4];
    const int* comp1  = (const int*)d_in[5];
    const int* w2_32  = (const int*)d_in[6];
    const int* b2     = (const int*)d_in[7];
    const int* comp2  = (const int*)d_in[8];
    const int* mul0   = (const int*)d_in[9];
    const int* mul1   = (const int*)d_in[10];
    const int* slope  = (const int*)d_in[11];

    const int nvox = in_sizes[0] / CCH;                 // 100000 (must be %16==0)
    const int wn = KK * CCH * CCH;                      // 110592 conv weights
    const size_t wext_b = (size_t)KK2 * CCH * CCH;      // 114688 per layer
    const size_t fbytes = (size_t)nvox * CCH;           // 6.4 MB per int8 feature map
    const size_t falign = (fbytes + 255) & ~(size_t)255;
    const size_t walign = (wext_b + 255) & ~(size_t)255;

    int8_t* q0;
    int8_t* q1;
    int8_t* w1e;
    int8_t* w2e;
    if (ws_size >= 2 * falign + 2 * walign + 256) {
        q0  = (int8_t*)d_ws;
        q1  = q0 + falign;
        w1e = q1 + falign;
        w2e = w1e + walign;
    } else {
        // stage q0 in d_out's bytes (dead after conv1; conv2 rewrites d_out fully)
        q0  = (int8_t*)d_out;
        q1  = (int8_t*)d_ws;
        w1e = q1 + falign;
        w2e = w1e + walign;
    }
    int8_t* zpage = w2e + walign;   // 256 B zero page

    const int pblocks = (wn + 255) / 256;
    k_pack8<<<pblocks, 256, 0, stream>>>(w1_32, w1e, wn);
    k_pack8<<<pblocks, 256, 0, stream>>>(w2_32, w2e, wn);
    k_packc<<<16, 256, 0, stream>>>(comp1, b1, w1e + (size_t)KK * CCH * CCH);
    k_packc<<<16, 256, 0, stream>>>(comp2, b2, w2e + (size_t)KK * CCH * CCH);

    {
        const int total4 = (nvox * CCH) / 4;
        int blocks = (total4 + 255) / 256;
        if (blocks > 4096) blocks = 4096;
        k_requant0<<<blocks, 256, 0, stream>>>(x32, mul0, (int*)q0, (int*)zpage, total4);
    }

    const int ntiles = nvox / 16;                       // 6250 (exact)
    int cblocks = 512;                                  // 2 resident blocks/CU (LDS-bound)
    if (cblocks > ntiles) cblocks = ntiles;
    k_conv_pipe<1><<<cblocks, 256, 0, stream>>>(q0, in_idx, mask, w1e,
                                                mul1, slope, nullptr, zpage,
                                                q1, nullptr, ntiles);
    k_conv_pipe<2><<<cblocks, 256, 0, stream>>>(q1, in_idx, mask, w2e,
                                                nullptr, nullptr, x32, zpage,
                                                nullptr, (int*)d_out, ntiles);
}

// Round 8
// 80.486 us; speedup vs baseline: 3.4744x; 1.0077x over previous
//
#include <hip/hip_runtime.h>
#include <stdint.h>

#define CCH 64
#define KK 27
#define KK2 28          // 27 conv slices + 1 affine (comp/bias) slice
#define SHIFT0 31
#define SHIFT1 31
#define PRELU_SHIFT 25

typedef int v4i __attribute__((ext_vector_type(4)));

__device__ __forceinline__ long long clip127(long long v) {
    return v > 127 ? 127 : (v < -127 ? -127 : v);
}

// repack int8-valued int32 array -> packed int8 (weights arrive as int32 on device)
__global__ void k_pack8(const int* __restrict__ src, int8_t* __restrict__ dst, int n) {
    int i = blockIdx.x * blockDim.x + threadIdx.x;
    if (i < n) dst[i] = (int8_t)src[i];
}

// build slice 27 of w_ext: B[j][col] encodes comp (split 4*hi+lo) and bias (64*hi+lo)
__global__ void k_packc(const int* __restrict__ comp, const int* __restrict__ bias,
                        int8_t* __restrict__ dst /* w_ext + 27*4096 */) {
    int t = blockIdx.x * blockDim.x + threadIdx.x;   // 0..4095
    if (t >= CCH * CCH) return;
    const int col = t >> 6;
    const int j   = t & 63;
    int v;
    if (j < 27)       v = comp[j * CCH + col] >> 2;          // pairs with A=4*mask
    else if (j < 54)  v = comp[(j - 27) * CCH + col] & 3;    // pairs with A=1*mask
    else if (j == 54) v = bias[col] >> 6;                    // pairs with A=64
    else if (j == 55) v = bias[col] & 63;                    // pairs with A=1
    else              v = 0;
    dst[col * 64 + j] = (int8_t)v;
}

// q0 = clip((x32 * mul0) >> 31) packed int8; also zero-fills the 256 B zero page
__global__ void k_requant0(const int* __restrict__ x,
                           const int* __restrict__ mulp,
                           int* __restrict__ q0,
                           int* __restrict__ zpage,
                           int total4) {
    if (blockIdx.x == 0 && threadIdx.x < 64) zpage[threadIdx.x] = 0;
    const long long mul = (long long)(*mulp);
    int i = blockIdx.x * blockDim.x + threadIdx.x;
    const int stride = gridDim.x * blockDim.x;
    for (; i < total4; i += stride) {
        int4 v = ((const int4*)x)[i];
        long long t;
        int r = 0;
        t = ((long long)v.x * mul) >> SHIFT0; t = clip127(t); r |= (int)(t & 0xff);
        t = ((long long)v.y * mul) >> SHIFT0; t = clip127(t); r |= (int)(t & 0xff) << 8;
        t = ((long long)v.z * mul) >> SHIFT0; t = clip127(t); r |= (int)(t & 0xff) << 16;
        t = ((long long)v.w * mul) >> SHIFT0; t = clip127(t); r |= (int)(t & 0xff) << 24;
        q0[i] = r;
    }
}

// affine A-fragment (slice 27) built in registers from the per-row mask bits:
// A[row][ch] = ch<27 ? 4*m[ch] : ch<54 ? m[ch-27] : ch==54 ? 64 : ch==55 ? 1 : 0
__device__ __forceinline__ v4i affine_frag(const int* __restrict__ idxm,
                                           int row, int q) {
    v4i r;
#pragma unroll
    for (int d = 0; d < 4; ++d) {
        int pk = 0;
#pragma unroll
        for (int b = 0; b < 4; ++b) {
            const int ch = q * 16 + d * 4 + b;
            int cc = (ch < 27) ? ch : ch - 27;
            cc = (cc > 26) ? 0 : cc;
            const int m = (idxm[row * KK + cc] >= 0) ? 1 : 0;
            const int bv = (ch < 27) ? (m << 2)
                         : (ch < 54) ? m
                         : (ch == 54) ? 64
                         : (ch == 55) ? 1 : 0;
            pk |= bv << (8 * b);
        }
        r[d] = pk;
    }
    return r;
}

// k-split MFMA conv, no LDS A-staging:
//  - 4 waves/block, wave wv owns k-slices [7wv, 7wv+7) for ALL 64 out channels
//  - A-fragments gathered straight to VGPRs (per-lane dwordx4), dbuf one tile ahead
//  - partial 16x64 sums reduced across waves through a small LDS buffer; wave g
//    finalizes/stores ch-group g (cols g*16..+16)
//  - raw s_barrier + lgkmcnt(0) only: prefetch loads stay in flight (no vmcnt)
// REQUIRES nvox % 16 == 0 (100000 = 6250*16).
template <int LAYER>
__global__ void __launch_bounds__(256, 2)
k_conv_ksplit(const int8_t* __restrict__ fin,   // [nvox*64] int8 activations
              const int* __restrict__ in_idx,   // [nvox*27]
              const int* __restrict__ mask,     // [nvox*27] (0/1)
              const int8_t* __restrict__ wext,  // [28*64*64] packed int8
              const int* __restrict__ mul1,     // [64]   (layer 1)
              const int* __restrict__ slopep,   // scalar (layer 1)
              const int* __restrict__ x32,      // [nvox*64] residual (layer 2)
              const int8_t* __restrict__ zpage, // 64+ B of zeros
              int8_t* __restrict__ q1out,       // layer-1 output
              int* __restrict__ out,            // layer-2 output
              int ntiles) {
    __shared__ int  s_idxm[2][16 * KK];          // [slot][row*27+k]: idx or -1
    __shared__ int2 s_red[4][4][2][64];          // [writer][group][pair][lane]

    const int tid  = threadIdx.x;
    const int lane = tid & 63;
    const int wv   = tid >> 6;            // wave id = k-range owner & epilogue group
    const int arow = lane & 15;           // A row / D col-in-group
    const int srow = lane >> 4;           // 16-B segment / D row block
    const int col  = wv * 16 + arow;      // epilogue column
    const int e0 = tid;
    const int e1 = (tid + 256 > 431) ? 431 : tid + 256;

    // --- per-block preloads: B-fragments for this wave's 7 slices x 4 groups ---
    v4i wreg[7][4];
#pragma unroll
    for (int j = 0; j < 7; ++j)
#pragma unroll
        for (int g = 0; g < 4; ++g)
            wreg[j][g] = *(const v4i*)(wext +
                ((size_t)((7 * wv + j) * CCH + g * 16 + arow)) * CCH + srow * 16);

    const int mul_r = (LAYER == 1) ? mul1[col] : 0;
    const long long slope = (LAYER == 1) ? (long long)(*slopep) : 0;

    const int stride = gridDim.x;
    const int t0 = blockIdx.x;
    if (t0 >= ntiles) return;
    const int cnt = (ntiles - 1 - t0) / stride + 1;

    v4i aA[7], aB[7];

#define GATHER_A(AN, SN)                                                       \
    _Pragma("unroll")                                                          \
    for (int j = 0; j < 7; ++j) {                                              \
        if (wv == 3 && j == 6) {                                               \
            AN[6] = affine_frag(&s_idxm[SN][0], arow, srow);                   \
        } else {                                                               \
            const int v_ = s_idxm[SN][arow * KK + (7 * wv + j)];               \
            const int8_t* src_ = (v_ >= 0)                                     \
                ? (fin + (size_t)v_ * CCH + srow * 16)                         \
                : (zpage + srow * 16);                                         \
            AN[j] = *(const v4i*)src_;                                         \
        }                                                                      \
    }

    // ---- prologue ----
    int pa0, pa1, pm0, pm1;
    {
        const size_t base = (size_t)t0 * (16 * KK);
        const int a0 = in_idx[base + e0], m0 = mask[base + e0];
        const int a1 = in_idx[base + e1], m1 = mask[base + e1];
        s_idxm[0][e0] = m0 ? a0 : -1;
        s_idxm[0][e1] = m1 ? a1 : -1;
    }
    {
        int t1c = t0 + stride; if (t1c >= ntiles) t1c = ntiles - 1;
        const size_t base = (size_t)t1c * (16 * KK);
        pa0 = in_idx[base + e0]; pm0 = mask[base + e0];
        pa1 = in_idx[base + e1]; pm1 = mask[base + e1];
    }
    __syncthreads();                       // slot0 visible (one-time vmcnt drain ok)
    GATHER_A(aA, 0)                        // tile t0 -> aA (in flight)
    s_idxm[1][e0] = pm0 ? pa0 : -1;        // publish idxm[t1] -> slot1
    s_idxm[1][e1] = pm1 ? pa1 : -1;
    asm volatile("s_waitcnt lgkmcnt(0)" ::: "memory");
    __builtin_amdgcn_s_barrier();          // raw: aA loads stay in flight

#define ITER(AC, AN, SC, SN)                                                   \
    do {                                                                       \
        /* (a) prefetch idx/mask of tile t+2 -> regs; x32 rows of tile t */    \
        int tp2_ = t + 2 * stride; if (tp2_ >= ntiles) tp2_ = ntiles - 1;      \
        const size_t b2_ = (size_t)tp2_ * (16 * KK);                           \
        const int qa0_ = in_idx[b2_ + e0], qm0_ = mask[b2_ + e0];              \
        const int qa1_ = in_idx[b2_ + e1], qm1_ = mask[b2_ + e1];              \
        const int nb_ = t * 16;                                                \
        int xr0_ = 0, xr1_ = 0, xr2_ = 0, xr3_ = 0;                            \
        if (LAYER == 2) {                                                      \
            xr0_ = x32[(size_t)(nb_ + srow * 4 + 0) * CCH + col];              \
            xr1_ = x32[(size_t)(nb_ + srow * 4 + 1) * CCH + col];              \
            xr2_ = x32[(size_t)(nb_ + srow * 4 + 2) * CCH + col];              \
            xr3_ = x32[(size_t)(nb_ + srow * 4 + 3) * CCH + col];              \
        }                                                                      \
        /* (b) issue next tile's A gathers into AN (reads slot SN) */          \
        GATHER_A(AN, SN)                                                       \
        __builtin_amdgcn_sched_barrier(0);                                     \
        /* (c) 28 MFMAs on AC (loads from previous iter, auto-vmcnt) */       \
        v4i acc0 = {0,0,0,0}, acc1 = {0,0,0,0}, acc2 = {0,0,0,0}, acc3 = {0,0,0,0}; \
        _Pragma("unroll")                                                      \
        for (int j = 0; j < 7; ++j) {                                          \
            acc0 = __builtin_amdgcn_mfma_i32_16x16x64_i8(AC[j], wreg[j][0], acc0, 0, 0, 0); \
            acc1 = __builtin_amdgcn_mfma_i32_16x16x64_i8(AC[j], wreg[j][1], acc1, 0, 0, 0); \
            acc2 = __builtin_amdgcn_mfma_i32_16x16x64_i8(AC[j], wreg[j][2], acc2, 0, 0, 0); \
            acc3 = __builtin_amdgcn_mfma_i32_16x16x64_i8(AC[j], wreg[j][3], acc3, 0, 0, 0); \
        }                                                                      \
        /* (d) write foreign partials (lane-consecutive int2 = conflict-free) */ \
        if (wv != 0) { s_red[wv][0][0][lane] = (int2){acc0[0], acc0[1]};       \
                       s_red[wv][0][1][lane] = (int2){acc0[2], acc0[3]}; }     \
        if (wv != 1) { s_red[wv][1][0][lane] = (int2){acc1[0], acc1[1]};       \
                       s_red[wv][1][1][lane] = (int2){acc1[2], acc1[3]}; }     \
        if (wv != 2) { s_red[wv][2][0][lane] = (int2){acc2[0], acc2[1]};       \
                       s_red[wv][2][1][lane] = (int2){acc2[2], acc2[3]}; }     \
        if (wv != 3) { s_red[wv][3][0][lane] = (int2){acc3[0], acc3[1]};       \
                       s_red[wv][3][1][lane] = (int2){acc3[2], acc3[3]}; }     \
        asm volatile("s_waitcnt lgkmcnt(0)" ::: "memory");                     \
        __builtin_amdgcn_s_barrier();                                          \
        /* (e) reduce own group, epilogue, stores (no vmem wait) */            \
        v4i tot;                                                               \
        if (wv == 0) tot = acc0; else if (wv == 1) tot = acc1;                 \
        else if (wv == 2) tot = acc2; else tot = acc3;                         \
        _Pragma("unroll")                                                      \
        for (int w = 0; w < 4; ++w) {                                          \
            if (w != wv) {                                                     \
                const int2 r0_ = s_red[w][wv][0][lane];                        \
                const int2 r1_ = s_red[w][wv][1][lane];                        \
                tot[0] += r0_.x; tot[1] += r0_.y;                              \
                tot[2] += r1_.x; tot[3] += r1_.y;                              \
            }                                                                  \
        }                                                                      \
        if (LAYER == 1) {                                                      \
            _Pragma("unroll")                                                  \
            for (int r = 0; r < 4; ++r) {                                      \
                long long p_ = tot[r];                                         \
                if (p_ < 0) p_ = (p_ * slope) >> PRELU_SHIFT;                  \
                long long q_ = (p_ * (long long)mul_r) >> SHIFT1;              \
                q_ = clip127(q_);                                              \
                q1out[(size_t)(nb_ + srow * 4 + r) * CCH + col] = (int8_t)q_;  \
            }                                                                  \
        } else {                                                               \
            out[(size_t)(nb_ + srow * 4 + 0) * CCH + col] = tot[0] + xr0_;     \
            out[(size_t)(nb_ + srow * 4 + 1) * CCH + col] = tot[1] + xr1_;     \
            out[(size_t)(nb_ + srow * 4 + 2) * CCH + col] = tot[2] + xr2_;     \
            out[(size_t)(nb_ + srow * 4 + 3) * CCH + col] = tot[3] + xr3_;     \
        }                                                                      \
        /* (f) publish idxm[t+2] into slot SC; end-of-tile barrier */          \
        s_idxm[SC][e0] = qm0_ ? qa0_ : -1;                                     \
        s_idxm[SC][e1] = qm1_ ? qa1_ : -1;                                     \
        asm volatile("s_waitcnt lgkmcnt(0)" ::: "memory");                     \
        __builtin_amdgcn_s_barrier();                                          \
    } while (0)

    // ---- main loop, 2x unrolled for static register double-buffering ----
    int t = t0;
    int i = 0;
    for (;;) {
        ITER(aA, aB, 0, 1);
        ++i; t += stride; if (i >= cnt) break;
        ITER(aB, aA, 1, 0);
        ++i; t += stride; if (i >= cnt) break;
    }
#undef ITER
#undef GATHER_A
}

extern "C" void kernel_launch(void* const* d_in, const int* in_sizes, int n_in,
                              void* d_out, int out_size, void* d_ws, size_t ws_size,
                              hipStream_t stream) {
    // ALL integer inputs arrive as int32 on device, regardless of reference dtype.
    const int* x32    = (const int*)d_in[0];
    const int* in_idx = (const int*)d_in[1];
    const int* mask   = (const int*)d_in[2];
    const int* w1_32  = (const int*)d_in[3];
    const int* b1     = (const int*)d_in[4];
    const int* comp1  = (const int*)d_in[5];
    const int* w2_32  = (const int*)d_in[6];
    const int* b2     = (const int*)d_in[7];
    const int* comp2  = (const int*)d_in[8];
    const int* mul0   = (const int*)d_in[9];
    const int* mul1   = (const int*)d_in[10];
    const int* slope  = (const int*)d_in[11];

    const int nvox = in_sizes[0] / CCH;                 // 100000 (must be %16==0)
    const int wn = KK * CCH * CCH;                      // 110592 conv weights
    const size_t wext_b = (size_t)KK2 * CCH * CCH;      // 114688 per layer
    const size_t fbytes = (size_t)nvox * CCH;           // 6.4 MB per int8 feature map
    const size_t falign = (fbytes + 255) & ~(size_t)255;
    const size_t walign = (wext_b + 255) & ~(size_t)255;

    int8_t* q0;
    int8_t* q1;
    int8_t* w1e;
    int8_t* w2e;
    if (ws_size >= 2 * falign + 2 * walign + 256) {
        q0  = (int8_t*)d_ws;
        q1  = q0 + falign;
        w1e = q1 + falign;
        w2e = w1e + walign;
    } else {
        // stage q0 in d_out's bytes (dead after conv1; conv2 rewrites d_out fully)
        q0  = (int8_t*)d_out;
        q1  = (int8_t*)d_ws;
        w1e = q1 + falign;
        w2e = w1e + walign;
    }
    int8_t* zpage = w2e + walign;   // 256 B zero page

    const int pblocks = (wn + 255) / 256;
    k_pack8<<<pblocks, 256, 0, stream>>>(w1_32, w1e, wn);
    k_pack8<<<pblocks, 256, 0, stream>>>(w2_32, w2e, wn);
    k_packc<<<16, 256, 0, stream>>>(comp1, b1, w1e + (size_t)KK * CCH * CCH);
    k_packc<<<16, 256, 0, stream>>>(comp2, b2, w2e + (size_t)KK * CCH * CCH);

    {
        const int total4 = (nvox * CCH) / 4;
        int blocks = (total4 + 255) / 256;
        if (blocks > 4096) blocks = 4096;
        k_requant0<<<blocks, 256, 0, stream>>>(x32, mul0, (int*)q0, (int*)zpage, total4);
    }

    const int ntiles = nvox / 16;                       // 6250 (exact)
    int cblocks = 512;                                  // 2 resident blocks/CU
    if (cblocks > ntiles) cblocks = ntiles;
    k_conv_ksplit<1><<<cblocks, 256, 0, stream>>>(q0, in_idx, mask, w1e,
                                                  mul1, slope, nullptr, zpage,
                                                  q1, nullptr, ntiles);
    k_conv_ksplit<2><<<cblocks, 256, 0, stream>>>(q1, in_idx, mask, w2e,
                                                  nullptr, nullptr, x32, zpage,
                                                  nullptr, (int*)d_out, ntiles);
}

// Round 9
// 65.515 us; speedup vs baseline: 4.2683x; 1.2285x over previous
//
#include <hip/hip_runtime.h>
#include <stdint.h>

#define CCH 64
#define KK 27
#define WN (KK * CCH * CCH)   // 110592

typedef int v4i __attribute__((ext_vector_type(4)));

// ---------------- prep: weight pack + affine slice + requant + zpage ----------------
// exact: (x*mul)>>31 == mulhi(x, mul<<1); (x*slope)>>25 == mulhi(x, slope<<7)
__global__ void __launch_bounds__(256) k_prep(
    const int* __restrict__ x32, const int* __restrict__ mul0p,
    const int* __restrict__ w1_32, const int* __restrict__ w2_32,
    const int* __restrict__ comp1, const int* __restrict__ b1,
    const int* __restrict__ comp2, const int* __restrict__ b2,
    int8_t* __restrict__ w1e, int8_t* __restrict__ w2e,
    int* __restrict__ q0, int* __restrict__ zpage,
    int prep_blocks, int total4)
{
    const int bid = blockIdx.x;
    if (bid < prep_blocks) {
        const int gtid = bid * 256 + threadIdx.x;
        if (gtid < WN) {
            w1e[gtid] = (int8_t)w1_32[gtid];
        } else if (gtid < 2 * WN) {
            w2e[gtid - WN] = (int8_t)w2_32[gtid - WN];
        } else if (gtid < 2 * WN + 8192) {
            int u = gtid - 2 * WN;
            const int which = u >> 12;
            u &= 4095;
            const int col = u >> 6, j = u & 63;
            const int* comp = which ? comp2 : comp1;
            const int* bias = which ? b2 : b1;
            int v;
            if (j < 27)       v = comp[j * CCH + col] >> 2;       // pairs A=4*mask
            else if (j < 54)  v = comp[(j - 27) * CCH + col] & 3; // pairs A=1*mask
            else if (j == 54) v = bias[col] >> 6;                 // pairs A=64
            else if (j == 55) v = bias[col] & 63;                 // pairs A=1
            else              v = 0;
            (which ? w2e : w1e)[27 * 4096 + col * 64 + j] = (int8_t)v;
        } else {
            const int u = gtid - 2 * WN - 8192;
            if (u < 64) zpage[u] = 0;
        }
    } else {
        const int i = (bid - prep_blocks) * 256 + threadIdx.x;
        if (i < total4) {
            const int mul2 = (*mul0p) << 1;
            const int4 v = ((const int4*)x32)[i];
            int r = 0, q;
            q = __mulhi(v.x, mul2); q = q > 127 ? 127 : (q < -127 ? -127 : q); r |= (q & 0xff);
            q = __mulhi(v.y, mul2); q = q > 127 ? 127 : (q < -127 ? -127 : q); r |= (q & 0xff) << 8;
            q = __mulhi(v.z, mul2); q = q > 127 ? 127 : (q < -127 ? -127 : q); r |= (q & 0xff) << 16;
            q = __mulhi(v.w, mul2); q = q > 127 ? 127 : (q < -127 ? -127 : q); r |= (q & 0xff) << 24;
            q0[i] = r;
        }
    }
}

// affine A-fragment (slice 27) from per-row mask bits:
// A[row][ch] = ch<27 ? 4*m[ch] : ch<54 ? m[ch-27] : ch==54 ? 64 : ch==55 ? 1 : 0
__device__ __forceinline__ v4i affine_frag(const int* __restrict__ idxm,
                                           int row, int q) {
    v4i r;
#pragma unroll
    for (int d = 0; d < 4; ++d) {
        int pk = 0;
#pragma unroll
        for (int b = 0; b < 4; ++b) {
            const int ch = q * 16 + d * 4 + b;
            int cc = (ch < 27) ? ch : ch - 27;
            cc = (cc > 26) ? 0 : cc;
            const int m = (idxm[row * KK + cc] >= 0) ? 1 : 0;
            const int bv = (ch < 27) ? (m << 2)
                         : (ch < 54) ? m
                         : (ch == 54) ? 64
                         : (ch == 55) ? 1 : 0;
            pk |= bv << (8 * b);
        }
        r[d] = pk;
    }
    return r;
}

// k-split MFMA conv, 1 barrier/tile, software-pipelined cross-wave reduction:
//  - wave wv owns k-slices [7wv,7wv+7) for all 64 out channels (wreg 7x4 frags)
//  - A-fragments gathered straight to VGPRs, register-double-buffered 1 tile ahead
//  - tile t's foreign partials written to s_red[t&1] in iter i; reduced + stored
//    in iter i+1 (own partial kept in accP) -> MFMA and reduce/epilogue decoupled
//  - only lgkmcnt(0)+s_barrier per tile; vmem loads stay in flight across it
// REQUIRES nvox % 16 == 0 (100000 = 6250*16).
template <int LAYER>
__global__ void __launch_bounds__(256, 2)
k_conv(const int8_t* __restrict__ fin,   // [nvox*64] int8 activations
       const int* __restrict__ in_idx,   // [nvox*27]
       const int* __restrict__ mask,     // [nvox*27] (0/1)
       const int8_t* __restrict__ wext,  // [28*64*64] packed int8
       const int* __restrict__ mul1,     // [64]   (layer 1)
       const int* __restrict__ slopep,   // scalar (layer 1)
       const int* __restrict__ x32,      // [nvox*64] residual (layer 2)
       const int8_t* __restrict__ zpage, // 64+ B zeros
       int8_t* __restrict__ q1out,       // layer-1 output
       int* __restrict__ out,            // layer-2 output
       int ntiles)
{
    __shared__ int s_idxm[2][16 * KK];        // [slot][row*27+k]: idx or -1
    __shared__ v4i s_red[2][4][4][64];        // [parity][writer][group][lane]

    const int tid  = threadIdx.x;
    const int lane = tid & 63;
    const int wv   = tid >> 6;
    const int arow = lane & 15;
    const int srow = lane >> 4;
    const int col  = wv * 16 + arow;
    const int e0 = tid;            // idxm entries 0..255
    const int e1 = tid + 176;      // idxm entries 176..431 (overlap benign: same values)

    v4i wreg[7][4];
#pragma unroll
    for (int j = 0; j < 7; ++j)
#pragma unroll
        for (int g = 0; g < 4; ++g)
            wreg[j][g] = *(const v4i*)(wext +
                ((size_t)((7 * wv + j) * CCH + g * 16 + arow)) * CCH + srow * 16);

    const int mul2     = (LAYER == 1) ? (mul1[col] << 1) : 0;
    const int slope128 = (LAYER == 1) ? ((*slopep) << 7) : 0;

    const int stride = gridDim.x;
    const int t0 = blockIdx.x;
    if (t0 >= ntiles) return;
    const int cnt = (ntiles - 1 - t0) / stride + 1;

    v4i aA[7], aB[7];
    v4i accP = {0, 0, 0, 0};

#define GATHER_A(AN, SN)                                                       \
    _Pragma("unroll")                                                          \
    for (int j = 0; j < 7; ++j) {                                              \
        if (wv == 3 && j == 6) {                                               \
            AN[6] = affine_frag(&s_idxm[SN][0], arow, srow);                   \
        } else {                                                               \
            const int v_ = s_idxm[SN][arow * KK + (7 * wv + j)];               \
            const int8_t* src_ = (v_ >= 0)                                     \
                ? (fin + (size_t)v_ * CCH + srow * 16)                         \
                : (zpage + srow * 16);                                         \
            AN[j] = *(const v4i*)src_;                                         \
        }                                                                      \
    }

#define EPILOGUE(TOT, NBP, X0, X1, X2, X3)                                     \
    if (LAYER == 1) {                                                          \
        _Pragma("unroll")                                                      \
        for (int r = 0; r < 4; ++r) {                                          \
            const int v_ = TOT[r];                                             \
            const int p_ = (v_ >= 0) ? v_ : __mulhi(v_, slope128);             \
            int q_ = __mulhi(p_, mul2);                                        \
            q_ = q_ > 127 ? 127 : (q_ < -127 ? -127 : q_);                     \
            q1out[(size_t)((NBP) + srow * 4 + r) * CCH + col] = (int8_t)q_;    \
        }                                                                      \
    } else {                                                                   \
        out[(size_t)((NBP) + srow * 4 + 0) * CCH + col] = TOT[0] + X0;         \
        out[(size_t)((NBP) + srow * 4 + 1) * CCH + col] = TOT[1] + X1;         \
        out[(size_t)((NBP) + srow * 4 + 2) * CCH + col] = TOT[2] + X2;         \
        out[(size_t)((NBP) + srow * 4 + 3) * CCH + col] = TOT[3] + X3;         \
    }

#define ITER(AC, AN, P, DO_EPI)                                                \
    do {                                                                       \
        /* (a) prefetch idx/mask tile t+2 -> regs; x32 rows of tile t-1 */     \
        int tp2_ = t + 2 * stride; if (tp2_ >= ntiles) tp2_ = ntiles - 1;      \
        const size_t b2_ = (size_t)tp2_ * (16 * KK);                           \
        const int qa0_ = in_idx[b2_ + e0], qm0_ = mask[b2_ + e0];              \
        const int qa1_ = in_idx[b2_ + e1], qm1_ = mask[b2_ + e1];              \
        const int nbp_ = (t - stride) * 16;                                    \
        int xr0_ = 0, xr1_ = 0, xr2_ = 0, xr3_ = 0;                            \
        if (DO_EPI && LAYER == 2) {                                            \
            xr0_ = x32[(size_t)(nbp_ + srow * 4 + 0) * CCH + col];             \
            xr1_ = x32[(size_t)(nbp_ + srow * 4 + 1) * CCH + col];             \
            xr2_ = x32[(size_t)(nbp_ + srow * 4 + 2) * CCH + col];             \
            xr3_ = x32[(size_t)(nbp_ + srow * 4 + 3) * CCH + col];             \
        }                                                                      \
        /* (b) issue next tile's A gathers */                                  \
        GATHER_A(AN, (P) ^ 1)                                                  \
        __builtin_amdgcn_sched_barrier(0);                                     \
        /* (c) 28 MFMAs on AC */                                               \
        v4i acc0 = {0,0,0,0}, acc1 = {0,0,0,0}, acc2 = {0,0,0,0}, acc3 = {0,0,0,0}; \
        _Pragma("unroll")                                                      \
        for (int j = 0; j < 7; ++j) {                                          \
            acc0 = __builtin_amdgcn_mfma_i32_16x16x64_i8(AC[j], wreg[j][0], acc0, 0, 0, 0); \
            acc1 = __builtin_amdgcn_mfma_i32_16x16x64_i8(AC[j], wreg[j][1], acc1, 0, 0, 0); \
            acc2 = __builtin_amdgcn_mfma_i32_16x16x64_i8(AC[j], wreg[j][2], acc2, 0, 0, 0); \
            acc3 = __builtin_amdgcn_mfma_i32_16x16x64_i8(AC[j], wreg[j][3], acc3, 0, 0, 0); \
        }                                                                      \
        /* (d) write foreign partials for tile t into s_red[P] */              \
        if (wv != 0) s_red[P][wv][0][lane] = acc0;                             \
        if (wv != 1) s_red[P][wv][1][lane] = acc1;                             \
        if (wv != 2) s_red[P][wv][2][lane] = acc2;                             \
        if (wv != 3) s_red[P][wv][3][lane] = acc3;                             \
        /* (e) reduce + store tile t-1 from s_red[P^1] + accP */               \
        if (DO_EPI) {                                                          \
            v4i tot = accP;                                                    \
            _Pragma("unroll")                                                  \
            for (int w = 0; w < 4; ++w) {                                      \
                if (w != wv) {                                                 \
                    const v4i r_ = s_red[(P) ^ 1][w][wv][lane];                \
                    tot[0] += r_[0]; tot[1] += r_[1];                          \
                    tot[2] += r_[2]; tot[3] += r_[3];                          \
                }                                                              \
            }                                                                  \
            EPILOGUE(tot, nbp_, xr0_, xr1_, xr2_, xr3_)                        \
        }                                                                      \
        /* (f) publish idxm[t+2] -> slot P; keep own partial */                \
        s_idxm[P][e0] = qm0_ ? qa0_ : -1;                                      \
        s_idxm[P][e1] = qm1_ ? qa1_ : -1;                                      \
        accP = (wv == 0) ? acc0 : (wv == 1) ? acc1 : (wv == 2) ? acc2 : acc3;  \
        asm volatile("s_waitcnt lgkmcnt(0)" ::: "memory");                     \
        __builtin_amdgcn_s_barrier();                                          \
    } while (0)

    // ---- prologue: idxm[t0]->slot0, idxm[t1]->slot1, gather A(t0)->aA ----
    int pa0, pa1, pm0, pm1;
    {
        const size_t base = (size_t)t0 * (16 * KK);
        const int a0 = in_idx[base + e0], m0 = mask[base + e0];
        const int a1 = in_idx[base + e1], m1 = mask[base + e1];
        s_idxm[0][e0] = m0 ? a0 : -1;
        s_idxm[0][e1] = m1 ? a1 : -1;
    }
    {
        int t1c = t0 + stride; if (t1c >= ntiles) t1c = ntiles - 1;
        const size_t base = (size_t)t1c * (16 * KK);
        pa0 = in_idx[base + e0]; pm0 = mask[base + e0];
        pa1 = in_idx[base + e1]; pm1 = mask[base + e1];
    }
    __syncthreads();
    GATHER_A(aA, 0)
    s_idxm[1][e0] = pm0 ? pa0 : -1;
    s_idxm[1][e1] = pm1 ? pa1 : -1;
    asm volatile("s_waitcnt lgkmcnt(0)" ::: "memory");
    __builtin_amdgcn_s_barrier();

    // ---- main loop ----
    int t = t0;
    ITER(aA, aB, 0, 0);
    t += stride;
    int i = 1;
    while (i < cnt) {
        ITER(aB, aA, 1, 1);
        ++i; t += stride; if (i >= cnt) break;
        ITER(aA, aB, 0, 1);
        ++i; t += stride;
    }

    // ---- drain: epilogue for the last tile ----
    {
        const int pl = (cnt - 1) & 1;
        const int nbl = (t0 + (cnt - 1) * stride) * 16;
        int x0 = 0, x1 = 0, x2 = 0, x3 = 0;
        if (LAYER == 2) {
            x0 = x32[(size_t)(nbl + srow * 4 + 0) * CCH + col];
            x1 = x32[(size_t)(nbl + srow * 4 + 1) * CCH + col];
            x2 = x32[(size_t)(nbl + srow * 4 + 2) * CCH + col];
            x3 = x32[(size_t)(nbl + srow * 4 + 3) * CCH + col];
        }
        v4i tot = accP;
#pragma unroll
        for (int w = 0; w < 4; ++w) {
            if (w != wv) {
                const v4i r_ = s_red[pl][w][wv][lane];
                tot[0] += r_[0]; tot[1] += r_[1];
                tot[2] += r_[2]; tot[3] += r_[3];
            }
        }
        EPILOGUE(tot, nbl, x0, x1, x2, x3)
    }
#undef ITER
#undef EPILOGUE
#undef GATHER_A
}

extern "C" void kernel_launch(void* const* d_in, const int* in_sizes, int n_in,
                              void* d_out, int out_size, void* d_ws, size_t ws_size,
                              hipStream_t stream) {
    // ALL integer inputs arrive as int32 on device, regardless of reference dtype.
    const int* x32    = (const int*)d_in[0];
    const int* in_idx = (const int*)d_in[1];
    const int* mask   = (const int*)d_in[2];
    const int* w1_32  = (const int*)d_in[3];
    const int* b1     = (const int*)d_in[4];
    const int* comp1  = (const int*)d_in[5];
    const int* w2_32  = (const int*)d_in[6];
    const int* b2     = (const int*)d_in[7];
    const int* comp2  = (const int*)d_in[8];
    const int* mul0   = (const int*)d_in[9];
    const int* mul1   = (const int*)d_in[10];
    const int* slope  = (const int*)d_in[11];

    const int nvox = in_sizes[0] / CCH;                 // 100000 (%16==0)
    const size_t wext_b = (size_t)28 * CCH * CCH;       // 114688 per layer
    const size_t fbytes = (size_t)nvox * CCH;           // 6.4 MB per int8 feature map
    const size_t falign = (fbytes + 255) & ~(size_t)255;
    const size_t walign = (wext_b + 255) & ~(size_t)255;

    int8_t* q0;
    int8_t* q1;
    int8_t* w1e;
    int8_t* w2e;
    if (ws_size >= 2 * falign + 2 * walign + 256) {
        q0  = (int8_t*)d_ws;
        q1  = q0 + falign;
        w1e = q1 + falign;
        w2e = w1e + walign;
    } else {
        // stage q0 in d_out's bytes (dead after conv1; conv2 rewrites d_out fully)
        q0  = (int8_t*)d_out;
        q1  = (int8_t*)d_ws;
        w1e = q1 + falign;
        w2e = w1e + walign;
    }
    int8_t* zpage = w2e + walign;   // 256 B zero page

    const int total4 = (nvox * CCH) / 4;                        // 1.6e6 int4-groups
    const int prep_blocks = (2 * WN + 8192 + 64 + 255) / 256;   // 897
    const int req_blocks  = (total4 + 255) / 256;               // 6250
    k_prep<<<prep_blocks + req_blocks, 256, 0, stream>>>(
        x32, mul0, w1_32, w2_32, comp1, b1, comp2, b2,
        w1e, w2e, (int*)q0, (int*)zpage, prep_blocks, total4);

    const int ntiles = nvox / 16;                       // 6250 (exact)
    int cblocks = 512;                                  // 2 resident blocks/CU
    if (cblocks > ntiles) cblocks = ntiles;
    k_conv<1><<<cblocks, 256, 0, stream>>>(q0, in_idx, mask, w1e,
                                           mul1, slope, nullptr, zpage,
                                           q1, nullptr, ntiles);
    k_conv<2><<<cblocks, 256, 0, stream>>>(q1, in_idx, mask, w2e,
                                           nullptr, nullptr, x32, zpage,
                                           nullptr, (int*)d_out, ntiles);
}

// Round 10
// 56.272 us; speedup vs baseline: 4.9694x; 1.1643x over previous
//
#include <hip/hip_runtime.h>
#include <stdint.h>

#define CCH 64
#define KK 27
#define WN (KK * CCH * CCH)   // 110592

typedef int v4i __attribute__((ext_vector_type(4)));

// ---------------- prep: weights + affine slice + af rows + requant + zero rows ----
// exact: (x*mul)>>31 == mulhi(x, mul<<1); (x*slope)>>25 == mulhi(x, slope<<7)
__global__ void __launch_bounds__(256) k_prep(
    const int* __restrict__ x32, const int* __restrict__ mul0p,
    const int* __restrict__ w1_32, const int* __restrict__ w2_32,
    const int* __restrict__ comp1, const int* __restrict__ b1,
    const int* __restrict__ comp2, const int* __restrict__ b2,
    const int* __restrict__ mask,
    int8_t* __restrict__ w1e, int8_t* __restrict__ w2e,
    int* __restrict__ q0, int* __restrict__ q1, int8_t* __restrict__ af,
    int pb1, int af_blocks, int nvox, int total4)
{
    const int bid = blockIdx.x;
    if (bid < pb1) {
        const int gtid = bid * 256 + threadIdx.x;
        if (gtid < WN) {
            w1e[gtid] = (int8_t)w1_32[gtid];
        } else if (gtid < 2 * WN) {
            w2e[gtid - WN] = (int8_t)w2_32[gtid - WN];
        } else if (gtid < 2 * WN + 8192) {
            int u = gtid - 2 * WN;
            const int which = u >> 12;
            u &= 4095;
            const int col = u >> 6, j = u & 63;
            const int* comp = which ? comp2 : comp1;
            const int* bias = which ? b2 : b1;
            int v;
            if (j < 27)       v = comp[j * CCH + col] >> 2;       // pairs A=4*mask
            else if (j < 54)  v = comp[(j - 27) * CCH + col] & 3; // pairs A=1*mask
            else if (j == 54) v = bias[col] >> 6;                 // pairs A=64
            else if (j == 55) v = bias[col] & 63;                 // pairs A=1
            else              v = 0;
            (which ? w2e : w1e)[27 * 4096 + col * 64 + j] = (int8_t)v;
        } else {
            const int u = gtid - 2 * WN - 8192;   // zero rows (row nvox of q0,q1)
            if (u < 16)       q0[(size_t)nvox * 16 + u] = 0;
            else if (u < 32)  q1[(size_t)nvox * 16 + (u - 16)] = 0;
        }
    } else if (bid < pb1 + af_blocks) {
        // affine A-rows: af[vox][j] = j<27?4m : j<54?m : j==54?64 : j==55?1 : 0
        const int vox = (bid - pb1) * 256 + threadIdx.x;
        if (vox < nvox) {
            int m[27];
#pragma unroll
            for (int k = 0; k < 27; ++k)
                m[k] = mask[(size_t)vox * 27 + k] ? 1 : 0;
            v4i d0, d1, d2, d3;
#pragma unroll
            for (int di = 0; di < 16; ++di) {
                int pk = 0;
#pragma unroll
                for (int b = 0; b < 4; ++b) {
                    const int ch = di * 4 + b;
                    int bv = 0;
                    if (ch < 27)       bv = m[ch] << 2;
                    else if (ch < 54)  bv = m[ch - 27];
                    else if (ch == 54) bv = 64;
                    else if (ch == 55) bv = 1;
                    pk |= bv << (8 * b);
                }
                if (di < 4)       d0[di] = pk;
                else if (di < 8)  d1[di - 4] = pk;
                else if (di < 12) d2[di - 8] = pk;
                else              d3[di - 12] = pk;
            }
            v4i* dst = (v4i*)(af + (size_t)vox * 64);
            dst[0] = d0; dst[1] = d1; dst[2] = d2; dst[3] = d3;
        }
    } else {
        const int i = (bid - pb1 - af_blocks) * 256 + threadIdx.x;
        if (i < total4) {
            const int mul2 = (*mul0p) << 1;
            const int4 v = ((const int4*)x32)[i];
            int r = 0, q;
            q = __mulhi(v.x, mul2); q = q > 127 ? 127 : (q < -127 ? -127 : q); r |= (q & 0xff);
            q = __mulhi(v.y, mul2); q = q > 127 ? 127 : (q < -127 ? -127 : q); r |= (q & 0xff) << 8;
            q = __mulhi(v.z, mul2); q = q > 127 ? 127 : (q < -127 ? -127 : q); r |= (q & 0xff) << 16;
            q = __mulhi(v.w, mul2); q = q > 127 ? 127 : (q < -127 ? -127 : q); r |= (q & 0xff) << 24;
            q0[i] = r;
        }
    }
}

// k-split MFMA conv, 1 barrier/tile, software-pipelined cross-wave reduction.
//  - wave wv owns k-slices [7wv,7wv+7) for all 64 out channels; wv3's 7th slice
//    is the affine slice whose A-rows are the precomputed af[] table
//  - s_off holds PRECOMPUTED byte offsets ((mask?idx:nvox)<<6); row nvox of fin
//    is zeroed, so gathers are branchless: load fin + off + srow*16
//  - A-fragments register-double-buffered one tile ahead; tile t's foreign
//    partials written to s_red[t&1], reduced + stored in the NEXT iteration
//  - one lgkmcnt(0)+s_barrier per tile; vmem loads stay in flight across it
// REQUIRES nvox % 16 == 0 (100000 = 6250*16).
template <int LAYER>
__global__ void __launch_bounds__(256, 2)
k_conv(const int8_t* __restrict__ fin,   // [(nvox+1)*64] int8 (row nvox = zeros)
       const int* __restrict__ in_idx,   // [nvox*27]
       const int* __restrict__ mask,     // [nvox*27] (0/1)
       const int8_t* __restrict__ wext,  // [28*64*64] packed int8
       const int8_t* __restrict__ af,    // [nvox*64] affine A-rows
       const int* __restrict__ mul1,     // [64]   (layer 1)
       const int* __restrict__ slopep,   // scalar (layer 1)
       const int* __restrict__ x32,      // [nvox*64] residual (layer 2)
       int8_t* __restrict__ q1out,       // layer-1 output
       int* __restrict__ out,            // layer-2 output
       int nvox, int ntiles)
{
    __shared__ int s_off[2][16 * KK];         // [slot][row*27+k]: byte offset
    __shared__ v4i s_red[2][4][4][64];        // [parity][writer][group][lane]

    const int tid  = threadIdx.x;
    const int lane = tid & 63;
    const int wv   = tid >> 6;
    const int arow = lane & 15;
    const int srow = lane >> 4;
    const int col  = wv * 16 + arow;
    const int e0 = tid;            // off entries 0..255
    const int e1 = tid + 176;      // off entries 176..431 (dup writes benign)

    v4i wreg[7][4];
#pragma unroll
    for (int j = 0; j < 7; ++j)
#pragma unroll
        for (int g = 0; g < 4; ++g)
            wreg[j][g] = *(const v4i*)(wext +
                ((size_t)((7 * wv + j) * CCH + g * 16 + arow)) * CCH + srow * 16);

    const int mul2     = (LAYER == 1) ? (mul1[col] << 1) : 0;
    const int slope128 = (LAYER == 1) ? ((*slopep) << 7) : 0;

    const int stride = gridDim.x;
    const int t0 = blockIdx.x;
    if (t0 >= ntiles) return;
    const int cnt = (ntiles - 1 - t0) / stride + 1;

    v4i aA[7], aB[7];
    v4i accP = {0, 0, 0, 0};

#define GATHER_A(AN, SN, NB)                                                   \
    _Pragma("unroll")                                                          \
    for (int j = 0; j < 7; ++j) {                                              \
        if (wv == 3 && j == 6) {                                               \
            AN[6] = *(const v4i*)(af + (size_t)((NB) + arow) * CCH + srow * 16); \
        } else {                                                               \
            const int off_ = s_off[SN][arow * KK + (7 * wv + j)];              \
            AN[j] = *(const v4i*)(fin + off_ + srow * 16);                     \
        }                                                                      \
    }

#define EPILOGUE(TOT, NBP, X0, X1, X2, X3)                                     \
    if (LAYER == 1) {                                                          \
        int8_t* rp_ = q1out + (size_t)((NBP) + srow * 4) * CCH + col;          \
        _Pragma("unroll")                                                      \
        for (int r = 0; r < 4; ++r) {                                          \
            const int v_ = TOT[r];                                             \
            const int p_ = (v_ >= 0) ? v_ : __mulhi(v_, slope128);             \
            int q_ = __mulhi(p_, mul2);                                        \
            q_ = q_ > 127 ? 127 : (q_ < -127 ? -127 : q_);                     \
            rp_[r * CCH] = (int8_t)q_;                                         \
        }                                                                      \
    } else {                                                                   \
        int* rp_ = out + (size_t)((NBP) + srow * 4) * CCH + col;               \
        rp_[0 * CCH] = TOT[0] + X0;                                            \
        rp_[1 * CCH] = TOT[1] + X1;                                            \
        rp_[2 * CCH] = TOT[2] + X2;                                            \
        rp_[3 * CCH] = TOT[3] + X3;                                            \
    }

#define ITER(AC, AN, P, DO_EPI)                                                \
    do {                                                                       \
        /* (a) prefetch off[t+2] -> regs; x32 rows of tile t-1 */              \
        int tp2_ = t + 2 * stride; if (tp2_ >= ntiles) tp2_ = ntiles - 1;      \
        const size_t b2_ = (size_t)tp2_ * (16 * KK);                           \
        const int qa0_ = in_idx[b2_ + e0], qm0_ = mask[b2_ + e0];              \
        const int qa1_ = in_idx[b2_ + e1], qm1_ = mask[b2_ + e1];              \
        const int nbp_ = (t - stride) * 16;                                    \
        int xr0_ = 0, xr1_ = 0, xr2_ = 0, xr3_ = 0;                            \
        if (DO_EPI && LAYER == 2) {                                            \
            const int* xp_ = x32 + (size_t)(nbp_ + srow * 4) * CCH + col;      \
            xr0_ = xp_[0 * CCH]; xr1_ = xp_[1 * CCH];                          \
            xr2_ = xp_[2 * CCH]; xr3_ = xp_[3 * CCH];                          \
        }                                                                      \
        /* (b) issue next tile's A gathers */                                  \
        GATHER_A(AN, (P) ^ 1, (t + stride < ntiles ? (t + stride) * 16 : (ntiles - 1) * 16)) \
        __builtin_amdgcn_sched_barrier(0);                                     \
        /* (c) 28 MFMAs on AC */                                               \
        v4i acc0 = {0,0,0,0}, acc1 = {0,0,0,0}, acc2 = {0,0,0,0}, acc3 = {0,0,0,0}; \
        _Pragma("unroll")                                                      \
        for (int j = 0; j < 7; ++j) {                                          \
            acc0 = __builtin_amdgcn_mfma_i32_16x16x64_i8(AC[j], wreg[j][0], acc0, 0, 0, 0); \
            acc1 = __builtin_amdgcn_mfma_i32_16x16x64_i8(AC[j], wreg[j][1], acc1, 0, 0, 0); \
            acc2 = __builtin_amdgcn_mfma_i32_16x16x64_i8(AC[j], wreg[j][2], acc2, 0, 0, 0); \
            acc3 = __builtin_amdgcn_mfma_i32_16x16x64_i8(AC[j], wreg[j][3], acc3, 0, 0, 0); \
        }                                                                      \
        /* (d) write foreign partials for tile t into s_red[P] */              \
        if (wv != 0) s_red[P][wv][0][lane] = acc0;                             \
        if (wv != 1) s_red[P][wv][1][lane] = acc1;                             \
        if (wv != 2) s_red[P][wv][2][lane] = acc2;                             \
        if (wv != 3) s_red[P][wv][3][lane] = acc3;                             \
        /* (e) reduce + store tile t-1 from s_red[P^1] + accP */               \
        if (DO_EPI) {                                                          \
            v4i tot = accP;                                                    \
            _Pragma("unroll")                                                  \
            for (int w = 0; w < 4; ++w) {                                      \
                if (w != wv) {                                                 \
                    const v4i r_ = s_red[(P) ^ 1][w][wv][lane];                \
                    tot[0] += r_[0]; tot[1] += r_[1];                          \
                    tot[2] += r_[2]; tot[3] += r_[3];                          \
                }                                                              \
            }                                                                  \
            EPILOGUE(tot, nbp_, xr0_, xr1_, xr2_, xr3_)                        \
        }                                                                      \
        /* (f) publish off[t+2] -> slot P; keep own partial */                 \
        s_off[P][e0] = (qm0_ ? qa0_ : nvox) << 6;                              \
        s_off[P][e1] = (qm1_ ? qa1_ : nvox) << 6;                              \
        accP = (wv == 0) ? acc0 : (wv == 1) ? acc1 : (wv == 2) ? acc2 : acc3;  \
        asm volatile("s_waitcnt lgkmcnt(0)" ::: "memory");                     \
        __builtin_amdgcn_s_barrier();                                          \
    } while (0)

    // ---- prologue: off[t0]->slot0, off[t1]->slot1, gather A(t0)->aA ----
    int pa0, pa1, pm0, pm1;
    {
        const size_t base = (size_t)t0 * (16 * KK);
        const int a0 = in_idx[base + e0], m0 = mask[base + e0];
        const int a1 = in_idx[base + e1], m1 = mask[base + e1];
        s_off[0][e0] = (m0 ? a0 : nvox) << 6;
        s_off[0][e1] = (m1 ? a1 : nvox) << 6;
    }
    {
        int t1c = t0 + stride; if (t1c >= ntiles) t1c = ntiles - 1;
        const size_t base = (size_t)t1c * (16 * KK);
        pa0 = in_idx[base + e0]; pm0 = mask[base + e0];
        pa1 = in_idx[base + e1]; pm1 = mask[base + e1];
    }
    __syncthreads();
    GATHER_A(aA, 0, t0 * 16)
    s_off[1][e0] = (pm0 ? pa0 : nvox) << 6;
    s_off[1][e1] = (pm1 ? pa1 : nvox) << 6;
    asm volatile("s_waitcnt lgkmcnt(0)" ::: "memory");
    __builtin_amdgcn_s_barrier();

    // ---- main loop ----
    int t = t0;
    ITER(aA, aB, 0, 0);
    t += stride;
    int i = 1;
    while (i < cnt) {
        ITER(aB, aA, 1, 1);
        ++i; t += stride; if (i >= cnt) break;
        ITER(aA, aB, 0, 1);
        ++i; t += stride;
    }

    // ---- drain: epilogue for the last tile ----
    {
        const int pl = (cnt - 1) & 1;
        const int nbl = (t0 + (cnt - 1) * stride) * 16;
        int x0 = 0, x1 = 0, x2 = 0, x3 = 0;
        if (LAYER == 2) {
            const int* xp_ = x32 + (size_t)(nbl + srow * 4) * CCH + col;
            x0 = xp_[0 * CCH]; x1 = xp_[1 * CCH];
            x2 = xp_[2 * CCH]; x3 = xp_[3 * CCH];
        }
        v4i tot = accP;
#pragma unroll
        for (int w = 0; w < 4; ++w) {
            if (w != wv) {
                const v4i r_ = s_red[pl][w][wv][lane];
                tot[0] += r_[0]; tot[1] += r_[1];
                tot[2] += r_[2]; tot[3] += r_[3];
            }
        }
        EPILOGUE(tot, nbl, x0, x1, x2, x3)
    }
#undef ITER
#undef EPILOGUE
#undef GATHER_A
}

extern "C" void kernel_launch(void* const* d_in, const int* in_sizes, int n_in,
                              void* d_out, int out_size, void* d_ws, size_t ws_size,
                              hipStream_t stream) {
    // ALL integer inputs arrive as int32 on device, regardless of reference dtype.
    const int* x32    = (const int*)d_in[0];
    const int* in_idx = (const int*)d_in[1];
    const int* mask   = (const int*)d_in[2];
    const int* w1_32  = (const int*)d_in[3];
    const int* b1     = (const int*)d_in[4];
    const int* comp1  = (const int*)d_in[5];
    const int* w2_32  = (const int*)d_in[6];
    const int* b2     = (const int*)d_in[7];
    const int* comp2  = (const int*)d_in[8];
    const int* mul0   = (const int*)d_in[9];
    const int* mul1   = (const int*)d_in[10];
    const int* slope  = (const int*)d_in[11];

    const int nvox = in_sizes[0] / CCH;                 // 100000 (%16==0)
    const size_t wext_b = (size_t)28 * CCH * CCH;       // 114688 per layer
    const size_t fbytes = (size_t)(nvox + 1) * CCH;     // +1 zero row
    const size_t falign = (fbytes + 255) & ~(size_t)255;
    const size_t walign = (wext_b + 255) & ~(size_t)255;

    int8_t* q0;
    int8_t* q1;
    int8_t* w1e;
    int8_t* w2e;
    int8_t* af;
    if (ws_size >= 3 * falign + 2 * walign) {
        q0  = (int8_t*)d_ws;
        q1  = q0 + falign;
        w1e = q1 + falign;
        w2e = w1e + walign;
        af  = w2e + walign;
    } else {
        // stage q0 in d_out's bytes (dead after conv1; conv2 rewrites d_out fully)
        q0  = (int8_t*)d_out;
        q1  = (int8_t*)d_ws;
        w1e = q1 + falign;
        w2e = w1e + walign;
        af  = w2e + walign;
    }

    const int total4 = (nvox * CCH) / 4;                          // 1.6e6
    const int pb1 = (2 * WN + 8192 + 32 + 255) / 256;             // 897
    const int af_blocks  = (nvox + 255) / 256;                    // 391
    const int req_blocks = (total4 + 255) / 256;                  // 6250
    k_prep<<<pb1 + af_blocks + req_blocks, 256, 0, stream>>>(
        x32, mul0, w1_32, w2_32, comp1, b1, comp2, b2, mask,
        w1e, w2e, (int*)q0, (int*)q1, af, pb1, af_blocks, nvox, total4);

    const int ntiles = nvox / 16;                       // 6250 (exact)
    int cblocks = 512;                                  // 2 resident blocks/CU
    if (cblocks > ntiles) cblocks = ntiles;
    k_conv<1><<<cblocks, 256, 0, stream>>>(q0, in_idx, mask, w1e, af,
                                           mul1, slope, nullptr,
                                           q1, nullptr, nvox, ntiles);
    k_conv<2><<<cblocks, 256, 0, stream>>>(q1, in_idx, mask, w2e, af,
                                           nullptr, nullptr, x32,
                                           nullptr, (int*)d_out, nvox, ntiles);
}